// Round 2
// baseline (894.402 us; speedup 1.0000x reference)
//
#include <hip/hip_runtime.h>
#include <math.h>

// Problem constants (fixed by setup_inputs)
constexpr int BB = 8;
constexpr int NN = 16384;
constexpr int SS = 2048;
constexpr int D1 = 128;
constexpr int D2 = 256;
constexpr int H1 = 256;   // layer-1 out channels
constexpr int H2 = 128;   // layer-2 out channels
constexpr int MM = BB * NN;  // 131072 total rows
constexpr int LDP = 132;  // padded LDS leading dim for 128-wide tiles

// ---------------------------------------------------------------- init
__global__ void k_init(float* __restrict__ st1, float* __restrict__ st2,
                       float* __restrict__ psum, int* __restrict__ pmax) {
    int t = threadIdx.x;
    if (t < 512) st1[t] = 0.f;
    if (t < 256) st2[t] = 0.f;
    if (t < 1024) { psum[t] = 0.f; pmax[t] = 0; }
}

// ---------------------------------------------------------------- 3-NN (fp64 exact ranking)
__global__ __launch_bounds__(256) void k_knn(const float* __restrict__ xyz1,
                                             const float* __restrict__ xyz2,
                                             int* __restrict__ idx,
                                             float* __restrict__ wgt) {
    __shared__ float sx[SS], sy[SS], sz[SS];   // 24 KB
    const int b = blockIdx.y;
    const int n0 = blockIdx.x * 256;
    const int tid = threadIdx.x;
    const float* xz2 = xyz2 + (size_t)b * SS * 3;
    for (int s = tid; s < SS; s += 256) {
        sx[s] = xz2[s * 3 + 0];
        sy[s] = xz2[s * 3 + 1];
        sz[s] = xz2[s * 3 + 2];
    }
    __syncthreads();
    const int n = n0 + tid;
    const float* q = xyz1 + ((size_t)b * NN + n) * 3;
    const double qx = (double)q[0], qy = (double)q[1], qz = (double)q[2];
    double t0 = 1e300, t1 = 1e300, t2 = 1e300;
    int i0 = 0, i1 = 0, i2 = 0;
    for (int s = 0; s < SS; ++s) {
        const double dx = qx - (double)sx[s];
        const double dy = qy - (double)sy[s];
        const double dz = qz - (double)sz[s];
        const double d = fma(dx, dx, fma(dy, dy, dz * dz));
        if (d < t2) {
            if (d < t0)      { t2 = t1; i2 = i1; t1 = t0; i1 = i0; t0 = d; i0 = s; }
            else if (d < t1) { t2 = t1; i2 = i1; t1 = d; i1 = s; }
            else             { t2 = d; i2 = s; }
        }
    }
    const double r0 = 1.0 / (t0 + 1e-8);
    const double r1 = 1.0 / (t1 + 1e-8);
    const double r2 = 1.0 / (t2 + 1e-8);
    const double inv = 1.0 / (r0 + r1 + r2);
    const size_t o = ((size_t)b * NN + n) * 3;
    idx[o + 0] = i0; idx[o + 1] = i1; idx[o + 2] = i2;
    wgt[o + 0] = (float)(r0 * inv);
    wgt[o + 1] = (float)(r1 * inv);
    wgt[o + 2] = (float)(r2 * inv);
}

// ---------------------------------------------------------------- GEMM1 (fused interp+concat) + stats1
// h1[row][c] = concat(p1[row], interp[row]) @ w1[c][:] + b1[c]
__global__ __launch_bounds__(256) void k_gemm1(const float* __restrict__ p1,
                                               const float* __restrict__ p2,
                                               const int* __restrict__ idx,
                                               const float* __restrict__ wgt,
                                               const float* __restrict__ w1p,
                                               const float* __restrict__ b1p,
                                               float* __restrict__ h1,
                                               float* __restrict__ st1) {
    __shared__ float smem[2 * 16 * LDP];          // As | Bs (reused as red)
    __shared__ int   sIdx[128 * 3];
    __shared__ float sWgt[128 * 3];
    float* As = smem;
    float* Bs = smem + 16 * LDP;

    const int tid = threadIdx.x;
    const int tx = tid & 15, ty = tid >> 4;
    const int row0 = blockIdx.x * 128;
    const int col0 = blockIdx.y * 128;
    const int b = row0 >> 14;                      // row0 / 16384
    const float* p2b = p2 + (size_t)b * SS * D2;

    for (int e = tid; e < 384; e += 256) {
        sIdx[e] = idx[(size_t)row0 * 3 + e];
        sWgt[e] = wgt[(size_t)row0 * 3 + e];
    }

    float acc[8][8];
#pragma unroll
    for (int i = 0; i < 8; ++i)
#pragma unroll
        for (int j = 0; j < 8; ++j) acc[i][j] = 0.f;

    const int r = tid >> 1;
    const int kh = (tid & 1) * 8;

    for (int kc = 0; kc < 24; ++kc) {
        const int kk = kc * 16;
        float4 v0, v1, u0, u1;
        if (kk < 128) {
            const float* src = p1 + (((size_t)(row0 + r)) << 7) + (kk + kh);
            v0 = *(const float4*)src;
            v1 = *(const float4*)(src + 4);
        } else {
            const int c2 = kk - 128 + kh;
            const int j0 = sIdx[r * 3 + 0], j1 = sIdx[r * 3 + 1], j2 = sIdx[r * 3 + 2];
            const float wa = sWgt[r * 3 + 0], wb = sWgt[r * 3 + 1], wc = sWgt[r * 3 + 2];
            const float* q0 = p2b + (((size_t)j0) << 8) + c2;
            const float* q1 = p2b + (((size_t)j1) << 8) + c2;
            const float* q2 = p2b + (((size_t)j2) << 8) + c2;
            float4 x0 = *(const float4*)q0, x1 = *(const float4*)(q0 + 4);
            float4 y0 = *(const float4*)q1, y1 = *(const float4*)(q1 + 4);
            float4 z0 = *(const float4*)q2, z1 = *(const float4*)(q2 + 4);
            v0.x = fmaf(wa, x0.x, fmaf(wb, y0.x, wc * z0.x));
            v0.y = fmaf(wa, x0.y, fmaf(wb, y0.y, wc * z0.y));
            v0.z = fmaf(wa, x0.z, fmaf(wb, y0.z, wc * z0.z));
            v0.w = fmaf(wa, x0.w, fmaf(wb, y0.w, wc * z0.w));
            v1.x = fmaf(wa, x1.x, fmaf(wb, y1.x, wc * z1.x));
            v1.y = fmaf(wa, x1.y, fmaf(wb, y1.y, wc * z1.y));
            v1.z = fmaf(wa, x1.z, fmaf(wb, y1.z, wc * z1.z));
            v1.w = fmaf(wa, x1.w, fmaf(wb, y1.w, wc * z1.w));
        }
        {
            const float* srcb = w1p + (size_t)(col0 + r) * 384 + (kk + kh);
            u0 = *(const float4*)srcb;
            u1 = *(const float4*)(srcb + 4);
        }
        __syncthreads();
        {
            float va[8] = {v0.x, v0.y, v0.z, v0.w, v1.x, v1.y, v1.z, v1.w};
            float ua[8] = {u0.x, u0.y, u0.z, u0.w, u1.x, u1.y, u1.z, u1.w};
#pragma unroll
            for (int j = 0; j < 8; ++j) {
                As[(kh + j) * LDP + r] = va[j];
                Bs[(kh + j) * LDP + r] = ua[j];
            }
        }
        __syncthreads();
#pragma unroll
        for (int k = 0; k < 16; ++k) {
            const float4 a0 = *(const float4*)&As[k * LDP + ty * 8];
            const float4 a1 = *(const float4*)&As[k * LDP + ty * 8 + 4];
            const float4 bq0 = *(const float4*)&Bs[k * LDP + tx * 8];
            const float4 bq1 = *(const float4*)&Bs[k * LDP + tx * 8 + 4];
            const float av[8] = {a0.x, a0.y, a0.z, a0.w, a1.x, a1.y, a1.z, a1.w};
            const float bv[8] = {bq0.x, bq0.y, bq0.z, bq0.w, bq1.x, bq1.y, bq1.z, bq1.w};
#pragma unroll
            for (int i = 0; i < 8; ++i)
#pragma unroll
                for (int j = 0; j < 8; ++j)
                    acc[i][j] = fmaf(av[i], bv[j], acc[i][j]);
        }
    }
    __syncthreads();   // before smem reuse

    float biasv[8];
#pragma unroll
    for (int j = 0; j < 8; ++j) biasv[j] = b1p[col0 + tx * 8 + j];
    float ssum[8], ssq[8];
#pragma unroll
    for (int j = 0; j < 8; ++j) { ssum[j] = 0.f; ssq[j] = 0.f; }
#pragma unroll
    for (int i = 0; i < 8; ++i) {
        const int grow = row0 + ty * 8 + i;
        float o[8];
#pragma unroll
        for (int j = 0; j < 8; ++j) {
            o[j] = acc[i][j] + biasv[j];
            ssum[j] += o[j];
            ssq[j] = fmaf(o[j], o[j], ssq[j]);
        }
        float* dst = h1 + (((size_t)grow) << 8) + col0 + tx * 8;
        *(float4*)dst = make_float4(o[0], o[1], o[2], o[3]);
        *(float4*)(dst + 4) = make_float4(o[4], o[5], o[6], o[7]);
    }
    float* red = smem;  // 4096 floats needed, 4224 available
#pragma unroll
    for (int j = 0; j < 8; ++j) {
        red[ty * 128 + tx * 8 + j] = ssum[j];
        red[2048 + ty * 128 + tx * 8 + j] = ssq[j];
    }
    __syncthreads();
    {
        const int c = tid & 127, which = tid >> 7;
        float tot = 0.f;
#pragma unroll
        for (int t = 0; t < 16; ++t) tot += red[which * 2048 + t * 128 + c];
        atomicAdd(&st1[which * H1 + col0 + c], tot);
    }
}

// ---------------------------------------------------------------- BN coef prep: a = g/sqrt(var+eps), b = be - mean*a
__global__ void k_bnprep(const float* __restrict__ st, const float* __restrict__ g,
                         const float* __restrict__ be, float* __restrict__ bn,
                         int C, float invM) {
    int c = blockIdx.x * blockDim.x + threadIdx.x;
    if (c < C) {
        float mean = st[c] * invM;
        float var = st[C + c] * invM - mean * mean;
        float a = g[c] / sqrtf(var + 1e-5f);
        bn[c] = a;
        bn[C + c] = fmaf(-mean, a, be[c]);
    }
}

// ---------------------------------------------------------------- GEMM2 (BN1+ReLU fused into A staging) + stats2
__global__ __launch_bounds__(256) void k_gemm2(const float* __restrict__ h1,
                                               const float* __restrict__ w2p,
                                               const float* __restrict__ b2p,
                                               const float* __restrict__ bn1,
                                               float* __restrict__ h2,
                                               float* __restrict__ st2) {
    __shared__ float smem[2 * 16 * LDP];
    __shared__ float sA[256], sB[256];
    float* As = smem;
    float* Bs = smem + 16 * LDP;

    const int tid = threadIdx.x;
    const int tx = tid & 15, ty = tid >> 4;
    const int row0 = blockIdx.x * 128;

    sA[tid] = bn1[tid];
    sB[tid] = bn1[256 + tid];
    __syncthreads();

    float acc[8][8];
#pragma unroll
    for (int i = 0; i < 8; ++i)
#pragma unroll
        for (int j = 0; j < 8; ++j) acc[i][j] = 0.f;

    const int r = tid >> 1;
    const int kh = (tid & 1) * 8;

    for (int kc = 0; kc < 16; ++kc) {
        const int kk = kc * 16;
        const float* src = h1 + (((size_t)(row0 + r)) << 8) + (kk + kh);
        float4 v0 = *(const float4*)src, v1 = *(const float4*)(src + 4);
        const float* srcb = w2p + (size_t)r * 256 + (kk + kh);
        float4 u0 = *(const float4*)srcb, u1 = *(const float4*)(srcb + 4);
        // BN1 + ReLU
        float va[8] = {v0.x, v0.y, v0.z, v0.w, v1.x, v1.y, v1.z, v1.w};
#pragma unroll
        for (int j = 0; j < 8; ++j)
            va[j] = fmaxf(fmaf(sA[kk + kh + j], va[j], sB[kk + kh + j]), 0.f);
        float ua[8] = {u0.x, u0.y, u0.z, u0.w, u1.x, u1.y, u1.z, u1.w};
        __syncthreads();
#pragma unroll
        for (int j = 0; j < 8; ++j) {
            As[(kh + j) * LDP + r] = va[j];
            Bs[(kh + j) * LDP + r] = ua[j];
        }
        __syncthreads();
#pragma unroll
        for (int k = 0; k < 16; ++k) {
            const float4 a0 = *(const float4*)&As[k * LDP + ty * 8];
            const float4 a1 = *(const float4*)&As[k * LDP + ty * 8 + 4];
            const float4 bq0 = *(const float4*)&Bs[k * LDP + tx * 8];
            const float4 bq1 = *(const float4*)&Bs[k * LDP + tx * 8 + 4];
            const float av[8] = {a0.x, a0.y, a0.z, a0.w, a1.x, a1.y, a1.z, a1.w};
            const float bv[8] = {bq0.x, bq0.y, bq0.z, bq0.w, bq1.x, bq1.y, bq1.z, bq1.w};
#pragma unroll
            for (int i = 0; i < 8; ++i)
#pragma unroll
                for (int j = 0; j < 8; ++j)
                    acc[i][j] = fmaf(av[i], bv[j], acc[i][j]);
        }
    }
    __syncthreads();

    float biasv[8];
#pragma unroll
    for (int j = 0; j < 8; ++j) biasv[j] = b2p[tx * 8 + j];
    float ssum[8], ssq[8];
#pragma unroll
    for (int j = 0; j < 8; ++j) { ssum[j] = 0.f; ssq[j] = 0.f; }
#pragma unroll
    for (int i = 0; i < 8; ++i) {
        const int grow = row0 + ty * 8 + i;
        float o[8];
#pragma unroll
        for (int j = 0; j < 8; ++j) {
            o[j] = acc[i][j] + biasv[j];
            ssum[j] += o[j];
            ssq[j] = fmaf(o[j], o[j], ssq[j]);
        }
        float* dst = h2 + (((size_t)grow) << 7) + tx * 8;
        *(float4*)dst = make_float4(o[0], o[1], o[2], o[3]);
        *(float4*)(dst + 4) = make_float4(o[4], o[5], o[6], o[7]);
    }
    float* red = smem;
#pragma unroll
    for (int j = 0; j < 8; ++j) {
        red[ty * 128 + tx * 8 + j] = ssum[j];
        red[2048 + ty * 128 + tx * 8 + j] = ssq[j];
    }
    __syncthreads();
    {
        const int c = tid & 127, which = tid >> 7;
        float tot = 0.f;
#pragma unroll
        for (int t = 0; t < 16; ++t) tot += red[which * 2048 + t * 128 + c];
        atomicAdd(&st2[which * H2 + c], tot);
    }
}

// ---------------------------------------------------------------- pool pass: per-(b,c) sum & max of relu(bn2(h2))
__global__ __launch_bounds__(256) void k_pool(const float* __restrict__ h2,
                                              const float* __restrict__ bn2,
                                              float* __restrict__ psum,
                                              int* __restrict__ pmax) {
    const int b = blockIdx.y;
    const int n0 = blockIdx.x * 256;
    const int tid = threadIdx.x;
    const int c = tid & 127, rh = tid >> 7;
    const float a = bn2[c], bc = bn2[128 + c];
    const float* base = h2 + (((size_t)b * NN + n0 + rh) << 7) + c;
    float s = 0.f, m = 0.f;
    for (int i = 0; i < 128; ++i) {
        float v = base[(size_t)i * 256];
        float x = fmaxf(fmaf(a, v, bc), 0.f);
        s += x;
        m = fmaxf(m, x);
    }
    __shared__ float rs[256];
    __shared__ float rm[256];
    rs[tid] = s; rm[tid] = m;
    __syncthreads();
    if (tid < 128) {
        float ts = rs[tid] + rs[tid + 128];
        float tm = fmaxf(rm[tid], rm[tid + 128]);
        atomicAdd(&psum[b * 128 + c], ts);
        atomicMax(&pmax[b * 128 + c], __float_as_int(tm));  // values >= 0: int compare valid
    }
}

// ---------------------------------------------------------------- SE attention: scale folded into bn2 coefs
__global__ __launch_bounds__(1024) void k_attn(const float* __restrict__ psum,
                                               const int* __restrict__ pmax,
                                               const float* __restrict__ fa1,
                                               const float* __restrict__ fa2,
                                               const float* __restrict__ bn2,
                                               float* __restrict__ sa,
                                               float* __restrict__ sb) {
    __shared__ float tS[128];   // (b*16+j): relu(avg.fa1_j) + relu(max.fa1_j)
    const int tid = threadIdx.x;
    if (tid < 128) {
        const int b = tid >> 4, j = tid & 15;
        float da = 0.f, dm = 0.f;
        for (int cc = 0; cc < 128; ++cc) {
            float f = fa1[j * 128 + cc];
            da = fmaf(psum[b * 128 + cc] * (1.0f / 16384.0f), f, da);
            dm = fmaf(__int_as_float(pmax[b * 128 + cc]), f, dm);
        }
        tS[tid] = fmaxf(da, 0.f) + fmaxf(dm, 0.f);
    }
    __syncthreads();
    const int b = tid >> 7, c = tid & 127;
    float s = 0.f;
#pragma unroll
    for (int j = 0; j < 16; ++j) s = fmaf(tS[b * 16 + j], fa2[c * 16 + j], s);
    const float sc = 1.f / (1.f + expf(-s));
    sa[b * 128 + c] = bn2[c] * sc;         // scale>0 so relu commutes: out = max(sa*h+sb, 0)
    sb[b * 128 + c] = bn2[128 + c] * sc;
}

// ---------------------------------------------------------------- final: out = max(sa*h2+sb, 0)
__global__ void k_final(const float* __restrict__ h2, const float* __restrict__ sa,
                        const float* __restrict__ sb, float* __restrict__ out) {
    const size_t i = (size_t)blockIdx.x * blockDim.x + threadIdx.x;  // float4 index
    const int c4 = (int)(i & 31);
    const size_t row = i >> 5;
    const int b = (int)(row >> 14);
    float4 h = ((const float4*)h2)[i];
    float4 A = ((const float4*)sa)[(b << 5) + c4];
    float4 Bv = ((const float4*)sb)[(b << 5) + c4];
    float4 o;
    o.x = fmaxf(fmaf(A.x, h.x, Bv.x), 0.f);
    o.y = fmaxf(fmaf(A.y, h.y, Bv.y), 0.f);
    o.z = fmaxf(fmaf(A.z, h.z, Bv.z), 0.f);
    o.w = fmaxf(fmaf(A.w, h.w, Bv.w), 0.f);
    ((float4*)out)[i] = o;
}

// ---------------------------------------------------------------- launch
extern "C" void kernel_launch(void* const* d_in, const int* in_sizes, int n_in,
                              void* d_out, int out_size, void* d_ws, size_t ws_size,
                              hipStream_t stream) {
    const float* xyz1 = (const float*)d_in[0];
    const float* xyz2 = (const float*)d_in[1];
    const float* p1   = (const float*)d_in[2];
    const float* p2   = (const float*)d_in[3];
    const float* w1   = (const float*)d_in[4];
    const float* b1   = (const float*)d_in[5];
    const float* g1   = (const float*)d_in[6];
    const float* be1  = (const float*)d_in[7];
    const float* w2   = (const float*)d_in[8];
    const float* b2   = (const float*)d_in[9];
    const float* g2   = (const float*)d_in[10];
    const float* be2  = (const float*)d_in[11];
    const float* fa1  = (const float*)d_in[12];
    const float* fa2  = (const float*)d_in[13];
    float* out = (float*)d_out;

    char* ws = (char*)d_ws;
    int*   idx  = (int*)ws;                                   // 393216 ints
    float* wgt  = (float*)(ws + 1572864);                     // 393216 floats
    float* h1   = (float*)(ws + 3145728);                     // 33.5M floats (134MB)
    float* h2   = (float*)(ws + 137363456);                   // 16.8M floats (67MB)
    float* st1  = (float*)(ws + 204472320);                   // 512
    float* bn1  = st1 + 512;                                  // 512
    float* st2  = bn1 + 512;                                  // 256
    float* bn2  = st2 + 256;                                  // 256
    float* psum = bn2 + 256;                                  // 1024
    int*   pmax = (int*)(psum + 1024);                        // 1024
    float* sa   = (float*)(pmax + 1024);                      // 1024
    float* sb   = sa + 1024;                                  // 1024

    k_init<<<1, 1024, 0, stream>>>(st1, st2, psum, pmax);
    k_knn<<<dim3(NN / 256, BB), 256, 0, stream>>>(xyz1, xyz2, idx, wgt);
    k_gemm1<<<dim3(MM / 128, 2), 256, 0, stream>>>(p1, p2, idx, wgt, w1, b1, h1, st1);
    k_bnprep<<<1, 256, 0, stream>>>(st1, g1, be1, bn1, 256, 1.0f / (float)MM);
    k_gemm2<<<dim3(MM / 128, 1), 256, 0, stream>>>(h1, w2, b2, bn1, h2, st2);
    k_bnprep<<<1, 128, 0, stream>>>(st2, g2, be2, bn2, 128, 1.0f / (float)MM);
    k_pool<<<dim3(NN / 256, BB), 256, 0, stream>>>(h2, bn2, psum, pmax);
    k_attn<<<1, 1024, 0, stream>>>(psum, pmax, fa1, fa2, bn2, sa, sb);
    k_final<<<(MM * H2 / 4) / 256, 256, 0, stream>>>(h2, sa, sb, out);
}

// Round 3
// 631.217 us; speedup vs baseline: 1.4169x; 1.4169x over previous
//
#include <hip/hip_runtime.h>
#include <math.h>

// Problem constants (fixed by setup_inputs)
constexpr int BB = 8;
constexpr int NN = 16384;
constexpr int SS = 2048;
constexpr int D2 = 256;
constexpr int H1 = 256;
constexpr int H2 = 128;
constexpr int MM = BB * NN;   // 131072 rows
constexpr int LDB = 40;       // LDS leading dim (bf16 elems): 80 B, 16B-aligned, uniform banks

typedef __attribute__((ext_vector_type(8))) short short8;    // bf16x8 frag (4 VGPRs)
typedef __attribute__((ext_vector_type(16))) float f32x16;   // 32x32 accumulator

__device__ __forceinline__ unsigned short f2b(float f) {     // fp32 -> bf16 RNE
    union { float f; unsigned u; } v; v.f = f;
    unsigned r = v.u + 0x7FFFu + ((v.u >> 16) & 1u);
    return (unsigned short)(r >> 16);
}
__device__ __forceinline__ unsigned pk2(float lo, float hi) {
    return (unsigned)f2b(lo) | ((unsigned)f2b(hi) << 16);
}

// ---------------------------------------------------------------- init
__global__ void k_init(float* __restrict__ st1, float* __restrict__ st2,
                       float* __restrict__ psum, int* __restrict__ pmax) {
    int t = threadIdx.x;
    if (t < 512) st1[t] = 0.f;
    if (t < 256) st2[t] = 0.f;
    if (t < 1024) { psum[t] = 0.f; pmax[t] = 0; }
}

// ---------------------------------------------------------------- weight fp32->bf16 prep
__global__ void k_wprep(const float* __restrict__ w1, const float* __restrict__ w2,
                        unsigned short* __restrict__ w1b, unsigned short* __restrict__ w2b) {
    int i = blockIdx.x * 256 + threadIdx.x;
    if (i < H1 * 384) w1b[i] = f2b(w1[i]);
    if (i < H2 * 256) w2b[i] = f2b(w2[i]);
}

// ---------------------------------------------------------------- 3-NN (fp64 exact ranking)
__global__ __launch_bounds__(256) void k_knn(const float* __restrict__ xyz1,
                                             const float* __restrict__ xyz2,
                                             int* __restrict__ idx,
                                             float* __restrict__ wgt) {
    __shared__ float sx[SS], sy[SS], sz[SS];
    const int b = blockIdx.y;
    const int n0 = blockIdx.x * 256;
    const int tid = threadIdx.x;
    const float* xz2 = xyz2 + (size_t)b * SS * 3;
    for (int s = tid; s < SS; s += 256) {
        sx[s] = xz2[s * 3 + 0];
        sy[s] = xz2[s * 3 + 1];
        sz[s] = xz2[s * 3 + 2];
    }
    __syncthreads();
    const int n = n0 + tid;
    const float* q = xyz1 + ((size_t)b * NN + n) * 3;
    const double qx = (double)q[0], qy = (double)q[1], qz = (double)q[2];
    double t0 = 1e300, t1 = 1e300, t2 = 1e300;
    int i0 = 0, i1 = 0, i2 = 0;
    for (int s = 0; s < SS; ++s) {
        const double dx = qx - (double)sx[s];
        const double dy = qy - (double)sy[s];
        const double dz = qz - (double)sz[s];
        const double d = fma(dx, dx, fma(dy, dy, dz * dz));
        if (d < t2) {
            if (d < t0)      { t2 = t1; i2 = i1; t1 = t0; i1 = i0; t0 = d; i0 = s; }
            else if (d < t1) { t2 = t1; i2 = i1; t1 = d; i1 = s; }
            else             { t2 = d; i2 = s; }
        }
    }
    const double r0 = 1.0 / (t0 + 1e-8);
    const double r1 = 1.0 / (t1 + 1e-8);
    const double r2 = 1.0 / (t2 + 1e-8);
    const double inv = 1.0 / (r0 + r1 + r2);
    const size_t o = ((size_t)b * NN + n) * 3;
    idx[o + 0] = i0; idx[o + 1] = i1; idx[o + 2] = i2;
    wgt[o + 0] = (float)(r0 * inv);
    wgt[o + 1] = (float)(r1 * inv);
    wgt[o + 2] = (float)(r2 * inv);
}

// ---------------------------------------------------------------- GEMM1: MFMA bf16, fused interp+concat, stats1
__global__ __launch_bounds__(256) void k_gemm1(const float* __restrict__ p1,
                                               const float* __restrict__ p2,
                                               const int* __restrict__ idx,
                                               const float* __restrict__ wgt,
                                               const unsigned short* __restrict__ w1b,
                                               const float* __restrict__ b1p,
                                               float* __restrict__ h1,
                                               float* __restrict__ st1) {
    __shared__ __align__(16) unsigned short As[128 * LDB];
    __shared__ __align__(16) unsigned short Bs[128 * LDB];
    __shared__ int   sIdx[384];
    __shared__ float sWgt[384];
    __shared__ float sSum[128], sSq[128];

    const int tid = threadIdx.x;
    const int row0 = blockIdx.x * 128;
    const int col0 = blockIdx.y * 128;
    const int b = row0 >> 14;
    const float* p2b = p2 + (size_t)b * (SS * D2);

    for (int e = tid; e < 384; e += 256) {
        sIdx[e] = idx[(size_t)row0 * 3 + e];
        sWgt[e] = wgt[(size_t)row0 * 3 + e];
    }
    if (tid < 128) { sSum[tid] = 0.f; sSq[tid] = 0.f; }

    const int wave = tid >> 6, lane = tid & 63;
    const int ln = lane & 31, hk = lane >> 5;
    const int wm = (wave & 1) << 6, wn = (wave >> 1) << 6;
    const int r = tid >> 1, half = tid & 1;

    f32x16 acc[2][2];
#pragma unroll
    for (int mt = 0; mt < 2; ++mt)
#pragma unroll
        for (int nt = 0; nt < 2; ++nt)
#pragma unroll
            for (int e = 0; e < 16; ++e) acc[mt][nt][e] = 0.f;

    for (int kc = 0; kc < 12; ++kc) {
        // ---- compute A bf16 (16 k-vals for row r) in regs
        uint4 pa0, pa1;
        if (kc < 4) {
            const float* src = p1 + (((size_t)(row0 + r)) << 7) + kc * 32 + half * 16;
            float4 a0 = *(const float4*)src, a1 = *(const float4*)(src + 4);
            float4 a2 = *(const float4*)(src + 8), a3 = *(const float4*)(src + 12);
            pa0 = make_uint4(pk2(a0.x, a0.y), pk2(a0.z, a0.w), pk2(a1.x, a1.y), pk2(a1.z, a1.w));
            pa1 = make_uint4(pk2(a2.x, a2.y), pk2(a2.z, a2.w), pk2(a3.x, a3.y), pk2(a3.z, a3.w));
        } else {
            const int c2 = kc * 32 - 128 + half * 16;
            const int j0 = sIdx[r * 3 + 0], j1 = sIdx[r * 3 + 1], j2 = sIdx[r * 3 + 2];
            const float wa = sWgt[r * 3 + 0], wb = sWgt[r * 3 + 1], wc = sWgt[r * 3 + 2];
            const float* q0 = p2b + (((size_t)j0) << 8) + c2;
            const float* q1 = p2b + (((size_t)j1) << 8) + c2;
            const float* q2 = p2b + (((size_t)j2) << 8) + c2;
            float v[16];
#pragma unroll
            for (int g = 0; g < 4; ++g) {
                float4 x = *(const float4*)(q0 + g * 4);
                float4 y = *(const float4*)(q1 + g * 4);
                float4 z = *(const float4*)(q2 + g * 4);
                v[g * 4 + 0] = fmaf(wa, x.x, fmaf(wb, y.x, wc * z.x));
                v[g * 4 + 1] = fmaf(wa, x.y, fmaf(wb, y.y, wc * z.y));
                v[g * 4 + 2] = fmaf(wa, x.z, fmaf(wb, y.z, wc * z.z));
                v[g * 4 + 3] = fmaf(wa, x.w, fmaf(wb, y.w, wc * z.w));
            }
            pa0 = make_uint4(pk2(v[0], v[1]), pk2(v[2], v[3]), pk2(v[4], v[5]), pk2(v[6], v[7]));
            pa1 = make_uint4(pk2(v[8], v[9]), pk2(v[10], v[11]), pk2(v[12], v[13]), pk2(v[14], v[15]));
        }
        // ---- B bf16 direct copy (w1b is [256][384] row-major = B^T)
        const unsigned short* bsrc = w1b + (size_t)(col0 + r) * 384 + kc * 32 + half * 16;
        const uint4 qb0 = *(const uint4*)bsrc;
        const uint4 qb1 = *(const uint4*)(bsrc + 8);

        __syncthreads();   // WAR: previous iteration's frag reads complete
        *(uint4*)&As[r * LDB + half * 16] = pa0;
        *(uint4*)&As[r * LDB + half * 16 + 8] = pa1;
        *(uint4*)&Bs[r * LDB + half * 16] = qb0;
        *(uint4*)&Bs[r * LDB + half * 16 + 8] = qb1;
        __syncthreads();

        short8 af[2][2], bfv[2][2];
#pragma unroll
        for (int mt = 0; mt < 2; ++mt)
#pragma unroll
            for (int ks = 0; ks < 2; ++ks)
                af[mt][ks] = *(const short8*)&As[(wm + mt * 32 + ln) * LDB + ks * 16 + hk * 8];
#pragma unroll
        for (int nt = 0; nt < 2; ++nt)
#pragma unroll
            for (int ks = 0; ks < 2; ++ks)
                bfv[nt][ks] = *(const short8*)&Bs[(wn + nt * 32 + ln) * LDB + ks * 16 + hk * 8];
#pragma unroll
        for (int mt = 0; mt < 2; ++mt)
#pragma unroll
            for (int nt = 0; nt < 2; ++nt)
#pragma unroll
                for (int ks = 0; ks < 2; ++ks)
                    acc[mt][nt] = __builtin_amdgcn_mfma_f32_32x32x16_bf16(
                        af[mt][ks], bfv[nt][ks], acc[mt][nt], 0, 0, 0);
    }

    // ---- epilogue: bias, stats, store fp32 h1
    float biasv[2];
#pragma unroll
    for (int nt = 0; nt < 2; ++nt) biasv[nt] = b1p[col0 + wn + nt * 32 + ln];
#pragma unroll
    for (int mt = 0; mt < 2; ++mt) {
#pragma unroll
        for (int nt = 0; nt < 2; ++nt) {
            const int col = col0 + wn + nt * 32 + ln;
            float ps = 0.f, pq = 0.f;
#pragma unroll
            for (int e = 0; e < 16; ++e) {
                const int rl = wm + mt * 32 + (e & 3) + ((e >> 2) << 3) + (hk << 2);
                const float o = acc[mt][nt][e] + biasv[nt];
                ps += o;
                pq = fmaf(o, o, pq);
                h1[(((size_t)(row0 + rl)) << 8) + col] = o;
            }
            atomicAdd(&sSum[wn + nt * 32 + ln], ps);
            atomicAdd(&sSq[wn + nt * 32 + ln], pq);
        }
    }
    __syncthreads();
    if (tid < 128) {
        atomicAdd(&st1[col0 + tid], sSum[tid]);
        atomicAdd(&st1[256 + col0 + tid], sSq[tid]);
    }
}

// ---------------------------------------------------------------- BN coef prep
__global__ void k_bnprep(const float* __restrict__ st, const float* __restrict__ g,
                         const float* __restrict__ be, float* __restrict__ bn,
                         int C, float invM) {
    int c = blockIdx.x * blockDim.x + threadIdx.x;
    if (c < C) {
        float mean = st[c] * invM;
        float var = st[C + c] * invM - mean * mean;
        float a = g[c] / sqrtf(var + 1e-5f);
        bn[c] = a;
        bn[C + c] = fmaf(-mean, a, be[c]);
    }
}

// ---------------------------------------------------------------- GEMM2: MFMA bf16, BN1+ReLU fused, stats2
__global__ __launch_bounds__(256) void k_gemm2(const float* __restrict__ h1,
                                               const unsigned short* __restrict__ w2b,
                                               const float* __restrict__ b2p,
                                               const float* __restrict__ bn1,
                                               float* __restrict__ h2,
                                               float* __restrict__ st2) {
    __shared__ __align__(16) unsigned short As[128 * LDB];
    __shared__ __align__(16) unsigned short Bs[128 * LDB];
    __shared__ float sBNa[256], sBNb[256];
    __shared__ float sSum[128], sSq[128];

    const int tid = threadIdx.x;
    const int row0 = blockIdx.x * 128;

    sBNa[tid] = bn1[tid];
    sBNb[tid] = bn1[256 + tid];
    if (tid < 128) { sSum[tid] = 0.f; sSq[tid] = 0.f; }

    const int wave = tid >> 6, lane = tid & 63;
    const int ln = lane & 31, hk = lane >> 5;
    const int wm = (wave & 1) << 6, wn = (wave >> 1) << 6;
    const int r = tid >> 1, half = tid & 1;

    f32x16 acc[2][2];
#pragma unroll
    for (int mt = 0; mt < 2; ++mt)
#pragma unroll
        for (int nt = 0; nt < 2; ++nt)
#pragma unroll
            for (int e = 0; e < 16; ++e) acc[mt][nt][e] = 0.f;

    __syncthreads();   // sBN visible

    for (int kc = 0; kc < 8; ++kc) {
        const int k0 = kc * 32 + half * 16;
        const float* src = h1 + (((size_t)(row0 + r)) << 8) + k0;
        float v[16];
#pragma unroll
        for (int g = 0; g < 4; ++g) {
            float4 x = *(const float4*)(src + g * 4);
            v[g * 4 + 0] = fmaxf(fmaf(sBNa[k0 + g * 4 + 0], x.x, sBNb[k0 + g * 4 + 0]), 0.f);
            v[g * 4 + 1] = fmaxf(fmaf(sBNa[k0 + g * 4 + 1], x.y, sBNb[k0 + g * 4 + 1]), 0.f);
            v[g * 4 + 2] = fmaxf(fmaf(sBNa[k0 + g * 4 + 2], x.z, sBNb[k0 + g * 4 + 2]), 0.f);
            v[g * 4 + 3] = fmaxf(fmaf(sBNa[k0 + g * 4 + 3], x.w, sBNb[k0 + g * 4 + 3]), 0.f);
        }
        uint4 pa0 = make_uint4(pk2(v[0], v[1]), pk2(v[2], v[3]), pk2(v[4], v[5]), pk2(v[6], v[7]));
        uint4 pa1 = make_uint4(pk2(v[8], v[9]), pk2(v[10], v[11]), pk2(v[12], v[13]), pk2(v[14], v[15]));
        const unsigned short* bsrc = w2b + (size_t)r * 256 + k0;
        const uint4 qb0 = *(const uint4*)bsrc;
        const uint4 qb1 = *(const uint4*)(bsrc + 8);

        __syncthreads();
        *(uint4*)&As[r * LDB + half * 16] = pa0;
        *(uint4*)&As[r * LDB + half * 16 + 8] = pa1;
        *(uint4*)&Bs[r * LDB + half * 16] = qb0;
        *(uint4*)&Bs[r * LDB + half * 16 + 8] = qb1;
        __syncthreads();

        short8 af[2][2], bfv[2][2];
#pragma unroll
        for (int mt = 0; mt < 2; ++mt)
#pragma unroll
            for (int ks = 0; ks < 2; ++ks)
                af[mt][ks] = *(const short8*)&As[(wm + mt * 32 + ln) * LDB + ks * 16 + hk * 8];
#pragma unroll
        for (int nt = 0; nt < 2; ++nt)
#pragma unroll
            for (int ks = 0; ks < 2; ++ks)
                bfv[nt][ks] = *(const short8*)&Bs[(wn + nt * 32 + ln) * LDB + ks * 16 + hk * 8];
#pragma unroll
        for (int mt = 0; mt < 2; ++mt)
#pragma unroll
            for (int nt = 0; nt < 2; ++nt)
#pragma unroll
                for (int ks = 0; ks < 2; ++ks)
                    acc[mt][nt] = __builtin_amdgcn_mfma_f32_32x32x16_bf16(
                        af[mt][ks], bfv[nt][ks], acc[mt][nt], 0, 0, 0);
    }

    float biasv[2];
#pragma unroll
    for (int nt = 0; nt < 2; ++nt) biasv[nt] = b2p[wn + nt * 32 + ln];
#pragma unroll
    for (int mt = 0; mt < 2; ++mt) {
#pragma unroll
        for (int nt = 0; nt < 2; ++nt) {
            const int col = wn + nt * 32 + ln;
            float ps = 0.f, pq = 0.f;
#pragma unroll
            for (int e = 0; e < 16; ++e) {
                const int rl = wm + mt * 32 + (e & 3) + ((e >> 2) << 3) + (hk << 2);
                const float o = acc[mt][nt][e] + biasv[nt];
                ps += o;
                pq = fmaf(o, o, pq);
                h2[(((size_t)(row0 + rl)) << 7) + col] = o;
            }
            atomicAdd(&sSum[col], ps);
            atomicAdd(&sSq[col], pq);
        }
    }
    __syncthreads();
    if (tid < 128) {
        atomicAdd(&st2[tid], sSum[tid]);
        atomicAdd(&st2[128 + tid], sSq[tid]);
    }
}

// ---------------------------------------------------------------- pool pass
__global__ __launch_bounds__(256) void k_pool(const float* __restrict__ h2,
                                              const float* __restrict__ bn2,
                                              float* __restrict__ psum,
                                              int* __restrict__ pmax) {
    const int b = blockIdx.y;
    const int n0 = blockIdx.x * 256;
    const int tid = threadIdx.x;
    const int c = tid & 127, rh = tid >> 7;
    const float a = bn2[c], bc = bn2[128 + c];
    const float* base = h2 + (((size_t)b * NN + n0 + rh) << 7) + c;
    float s = 0.f, m = 0.f;
    for (int i = 0; i < 128; ++i) {
        float v = base[(size_t)i * 256];
        float x = fmaxf(fmaf(a, v, bc), 0.f);
        s += x;
        m = fmaxf(m, x);
    }
    __shared__ float rs[256];
    __shared__ float rm[256];
    rs[tid] = s; rm[tid] = m;
    __syncthreads();
    if (tid < 128) {
        float ts = rs[tid] + rs[tid + 128];
        float tm = fmaxf(rm[tid], rm[tid + 128]);
        atomicAdd(&psum[b * 128 + c], ts);
        atomicMax(&pmax[b * 128 + c], __float_as_int(tm));
    }
}

// ---------------------------------------------------------------- SE attention
__global__ __launch_bounds__(1024) void k_attn(const float* __restrict__ psum,
                                               const int* __restrict__ pmax,
                                               const float* __restrict__ fa1,
                                               const float* __restrict__ fa2,
                                               const float* __restrict__ bn2,
                                               float* __restrict__ sa,
                                               float* __restrict__ sb) {
    __shared__ float tS[128];
    const int tid = threadIdx.x;
    if (tid < 128) {
        const int b = tid >> 4, j = tid & 15;
        float da = 0.f, dm = 0.f;
        for (int cc = 0; cc < 128; ++cc) {
            float f = fa1[j * 128 + cc];
            da = fmaf(psum[b * 128 + cc] * (1.0f / 16384.0f), f, da);
            dm = fmaf(__int_as_float(pmax[b * 128 + cc]), f, dm);
        }
        tS[tid] = fmaxf(da, 0.f) + fmaxf(dm, 0.f);
    }
    __syncthreads();
    const int b = tid >> 7, c = tid & 127;
    float s = 0.f;
#pragma unroll
    for (int j = 0; j < 16; ++j) s = fmaf(tS[b * 16 + j], fa2[c * 16 + j], s);
    const float sc = 1.f / (1.f + expf(-s));
    sa[b * 128 + c] = bn2[c] * sc;
    sb[b * 128 + c] = bn2[128 + c] * sc;
}

// ---------------------------------------------------------------- final
__global__ void k_final(const float* __restrict__ h2, const float* __restrict__ sa,
                        const float* __restrict__ sb, float* __restrict__ out) {
    const size_t i = (size_t)blockIdx.x * blockDim.x + threadIdx.x;
    const int c4 = (int)(i & 31);
    const size_t row = i >> 5;
    const int b = (int)(row >> 14);
    float4 h = ((const float4*)h2)[i];
    float4 A = ((const float4*)sa)[(b << 5) + c4];
    float4 Bv = ((const float4*)sb)[(b << 5) + c4];
    float4 o;
    o.x = fmaxf(fmaf(A.x, h.x, Bv.x), 0.f);
    o.y = fmaxf(fmaf(A.y, h.y, Bv.y), 0.f);
    o.z = fmaxf(fmaf(A.z, h.z, Bv.z), 0.f);
    o.w = fmaxf(fmaf(A.w, h.w, Bv.w), 0.f);
    ((float4*)out)[i] = o;
}

// ---------------------------------------------------------------- launch
extern "C" void kernel_launch(void* const* d_in, const int* in_sizes, int n_in,
                              void* d_out, int out_size, void* d_ws, size_t ws_size,
                              hipStream_t stream) {
    const float* xyz1 = (const float*)d_in[0];
    const float* xyz2 = (const float*)d_in[1];
    const float* p1   = (const float*)d_in[2];
    const float* p2   = (const float*)d_in[3];
    const float* w1   = (const float*)d_in[4];
    const float* b1   = (const float*)d_in[5];
    const float* g1   = (const float*)d_in[6];
    const float* be1  = (const float*)d_in[7];
    const float* w2   = (const float*)d_in[8];
    const float* b2   = (const float*)d_in[9];
    const float* g2   = (const float*)d_in[10];
    const float* be2  = (const float*)d_in[11];
    const float* fa1  = (const float*)d_in[12];
    const float* fa2  = (const float*)d_in[13];
    float* out = (float*)d_out;

    char* ws = (char*)d_ws;
    int*   idx  = (int*)ws;                                   // 393216 ints
    float* wgt  = (float*)(ws + 1572864);                     // 393216 floats
    float* h1   = (float*)(ws + 3145728);                     // 134 MB fp32
    float* h2   = (float*)(ws + 137363456);                   // 67 MB fp32
    float* st1  = (float*)(ws + 204472320);                   // 512
    float* bn1  = st1 + 512;                                  // 512
    float* st2  = bn1 + 512;                                  // 256
    float* bn2  = st2 + 256;                                  // 256
    float* psum = bn2 + 256;                                  // 1024
    int*   pmax = (int*)(psum + 1024);                        // 1024
    float* sa   = (float*)(pmax + 1024);                      // 1024
    float* sb   = sa + 1024;                                  // 1024
    unsigned short* w1b = (unsigned short*)(sb + 1024);       // 98304 bf16
    unsigned short* w2b = w1b + 98304;                        // 32768 bf16

    k_init<<<1, 1024, 0, stream>>>(st1, st2, psum, pmax);
    k_wprep<<<(H1 * 384 + 255) / 256, 256, 0, stream>>>(w1, w2, w1b, w2b);
    k_knn<<<dim3(NN / 256, BB), 256, 0, stream>>>(xyz1, xyz2, idx, wgt);
    k_gemm1<<<dim3(MM / 128, 2), 256, 0, stream>>>(p1, p2, idx, wgt, w1b, b1, h1, st1);
    k_bnprep<<<1, 256, 0, stream>>>(st1, g1, be1, bn1, 256, 1.0f / (float)MM);
    k_gemm2<<<dim3(MM / 128, 1), 256, 0, stream>>>(h1, w2b, b2, bn1, h2, st2);
    k_bnprep<<<1, 128, 0, stream>>>(st2, g2, be2, bn2, 128, 1.0f / (float)MM);
    k_pool<<<dim3(NN / 256, BB), 256, 0, stream>>>(h2, bn2, psum, pmax);
    k_attn<<<1, 1024, 0, stream>>>(psum, pmax, fa1, fa2, bn2, sa, sb);
    k_final<<<(MM * H2 / 4) / 256, 256, 0, stream>>>(h2, sa, sb, out);
}

// Round 4
// 506.874 us; speedup vs baseline: 1.7645x; 1.2453x over previous
//
#include <hip/hip_runtime.h>
#include <math.h>

// Problem constants (fixed by setup_inputs)
constexpr int BB = 8;
constexpr int NN = 16384;
constexpr int SS = 2048;
constexpr int D2 = 256;
constexpr int H1 = 256;
constexpr int H2 = 128;
constexpr int MM = BB * NN;   // 131072 rows
constexpr int LDB = 40;       // LDS leading dim (bf16 elems): 80 B, 16B-aligned, uniform banks

typedef __attribute__((ext_vector_type(8))) short short8;    // bf16x8 frag (4 VGPRs)
typedef __attribute__((ext_vector_type(16))) float f32x16;   // 32x32 accumulator

__device__ __forceinline__ unsigned short f2b(float f) {     // fp32 -> bf16 RNE
    union { float f; unsigned u; } v; v.f = f;
    unsigned r = v.u + 0x7FFFu + ((v.u >> 16) & 1u);
    return (unsigned short)(r >> 16);
}
__device__ __forceinline__ unsigned pk2(float lo, float hi) {
    return (unsigned)f2b(lo) | ((unsigned)f2b(hi) << 16);
}

// ---------------------------------------------------------------- init
__global__ void k_init(float* __restrict__ st1, float* __restrict__ st2,
                       float* __restrict__ psum, int* __restrict__ pmax) {
    int t = threadIdx.x;
    if (t < 512) st1[t] = 0.f;
    if (t < 256) st2[t] = 0.f;
    if (t < 1024) { psum[t] = 0.f; pmax[t] = 0; }
}

// ---------------------------------------------------------------- weight fp32->bf16 prep
__global__ void k_wprep(const float* __restrict__ w1, const float* __restrict__ w2,
                        unsigned short* __restrict__ w1b, unsigned short* __restrict__ w2b) {
    int i = blockIdx.x * 256 + threadIdx.x;
    if (i < H1 * 384) w1b[i] = f2b(w1[i]);
    if (i < H2 * 256) w2b[i] = f2b(w2[i]);
}

// ---------------------------------------------------------------- 3-NN
// fp32 exact-form scan with packed uint keys (branchless top-5/chunk),
// 4-way S-split per query, fp64 refine of 20 candidates -> exact top-3.
__global__ __launch_bounds__(256) void k_knn(const float* __restrict__ xyz1,
                                             const float* __restrict__ xyz2,
                                             int* __restrict__ idx,
                                             float* __restrict__ wgt) {
    __shared__ float sx[SS], sy[SS], sz[SS];      // 24 KB
    __shared__ unsigned cand[64][20];             // 5 KB: [query][chunk*5+t]
    const int b = blockIdx.y;
    const int tid = threadIdx.x;
    const int ql = tid & 63;                      // query-local
    const int chunk = tid >> 6;                   // S-chunk 0..3
    const int n = blockIdx.x * 64 + ql;

    const float* xz2 = xyz2 + (size_t)b * SS * 3;
    for (int s = tid; s < SS; s += 256) {
        sx[s] = xz2[s * 3 + 0];
        sy[s] = xz2[s * 3 + 1];
        sz[s] = xz2[s * 3 + 2];
    }
    __syncthreads();

    const float* q = xyz1 + ((size_t)b * NN + n) * 3;
    const float qx = q[0], qy = q[1], qz = q[2];

    unsigned k0 = 0xFFFFFFFFu, k1 = 0xFFFFFFFFu, k2 = 0xFFFFFFFFu,
             k3 = 0xFFFFFFFFu, k4 = 0xFFFFFFFFu;
    const int s0 = chunk * 512;
#pragma unroll 4
    for (int j = 0; j < 512; ++j) {
        const int s = s0 + j;
        const float dx = qx - sx[s];
        const float dy = qy - sy[s];
        const float dz = qz - sz[s];
        const float d = fmaf(dx, dx, fmaf(dy, dy, dz * dz));
        // fp32 positive -> uint order-isomorphic; drop 9 mantissa bits for idx
        const unsigned key = (__float_as_uint(d) & 0xFFFFFE00u) | (unsigned)j;
        const bool c0 = key < k0, c1 = key < k1, c2 = key < k2,
                   c3 = key < k3, c4 = key < k4;
        k4 = c4 ? (c3 ? k3 : key) : k4;
        k3 = c3 ? (c2 ? k2 : key) : k3;
        k2 = c2 ? (c1 ? k1 : key) : k2;
        k1 = c1 ? (c0 ? k0 : key) : k1;
        k0 = c0 ? key : k0;
    }
    unsigned* cq = cand[ql] + chunk * 5;
    cq[0] = k0; cq[1] = k1; cq[2] = k2; cq[3] = k3; cq[4] = k4;
    __syncthreads();

    if (tid < 64) {
        const double qxd = (double)qx, qyd = (double)qy, qzd = (double)qz;
        double t0 = 1e300, t1 = 1e300, t2 = 1e300;
        int i0 = 0, i1 = 0, i2 = 0;
#pragma unroll
        for (int ch = 0; ch < 4; ++ch) {
#pragma unroll
            for (int t = 0; t < 5; ++t) {
                const int s = ch * 512 + (int)(cand[tid][ch * 5 + t] & 0x1FFu);
                const double dx = qxd - (double)sx[s];
                const double dy = qyd - (double)sy[s];
                const double dz = qzd - (double)sz[s];
                const double d = fma(dx, dx, fma(dy, dy, dz * dz));
                if (d < t2) {
                    if (d < t0)      { t2 = t1; i2 = i1; t1 = t0; i1 = i0; t0 = d; i0 = s; }
                    else if (d < t1) { t2 = t1; i2 = i1; t1 = d; i1 = s; }
                    else             { t2 = d; i2 = s; }
                }
            }
        }
        const double r0 = 1.0 / (t0 + 1e-8);
        const double r1 = 1.0 / (t1 + 1e-8);
        const double r2 = 1.0 / (t2 + 1e-8);
        const double inv = 1.0 / (r0 + r1 + r2);
        const size_t o = ((size_t)b * NN + n) * 3;
        idx[o + 0] = i0; idx[o + 1] = i1; idx[o + 2] = i2;
        wgt[o + 0] = (float)(r0 * inv);
        wgt[o + 1] = (float)(r1 * inv);
        wgt[o + 2] = (float)(r2 * inv);
    }
}

// ---------------------------------------------------------------- GEMM1: MFMA bf16, fused interp+concat, stats1
__global__ __launch_bounds__(256) void k_gemm1(const float* __restrict__ p1,
                                               const float* __restrict__ p2,
                                               const int* __restrict__ idx,
                                               const float* __restrict__ wgt,
                                               const unsigned short* __restrict__ w1b,
                                               const float* __restrict__ b1p,
                                               float* __restrict__ h1,
                                               float* __restrict__ st1) {
    __shared__ __align__(16) unsigned short As[128 * LDB];
    __shared__ __align__(16) unsigned short Bs[128 * LDB];
    __shared__ int   sIdx[384];
    __shared__ float sWgt[384];
    __shared__ float sSum[128], sSq[128];

    const int tid = threadIdx.x;
    const int row0 = blockIdx.x * 128;
    const int col0 = blockIdx.y * 128;
    const int b = row0 >> 14;
    const float* p2b = p2 + (size_t)b * (SS * D2);

    for (int e = tid; e < 384; e += 256) {
        sIdx[e] = idx[(size_t)row0 * 3 + e];
        sWgt[e] = wgt[(size_t)row0 * 3 + e];
    }
    if (tid < 128) { sSum[tid] = 0.f; sSq[tid] = 0.f; }

    const int wave = tid >> 6, lane = tid & 63;
    const int ln = lane & 31, hk = lane >> 5;
    const int wm = (wave & 1) << 6, wn = (wave >> 1) << 6;
    const int r = tid >> 1, half = tid & 1;

    f32x16 acc[2][2];
#pragma unroll
    for (int mt = 0; mt < 2; ++mt)
#pragma unroll
        for (int nt = 0; nt < 2; ++nt)
#pragma unroll
            for (int e = 0; e < 16; ++e) acc[mt][nt][e] = 0.f;

    for (int kc = 0; kc < 12; ++kc) {
        // ---- compute A bf16 (16 k-vals for row r) in regs
        uint4 pa0, pa1;
        if (kc < 4) {
            const float* src = p1 + (((size_t)(row0 + r)) << 7) + kc * 32 + half * 16;
            float4 a0 = *(const float4*)src, a1 = *(const float4*)(src + 4);
            float4 a2 = *(const float4*)(src + 8), a3 = *(const float4*)(src + 12);
            pa0 = make_uint4(pk2(a0.x, a0.y), pk2(a0.z, a0.w), pk2(a1.x, a1.y), pk2(a1.z, a1.w));
            pa1 = make_uint4(pk2(a2.x, a2.y), pk2(a2.z, a2.w), pk2(a3.x, a3.y), pk2(a3.z, a3.w));
        } else {
            const int c2 = kc * 32 - 128 + half * 16;
            const int j0 = sIdx[r * 3 + 0], j1 = sIdx[r * 3 + 1], j2 = sIdx[r * 3 + 2];
            const float wa = sWgt[r * 3 + 0], wb = sWgt[r * 3 + 1], wc = sWgt[r * 3 + 2];
            const float* q0 = p2b + (((size_t)j0) << 8) + c2;
            const float* q1 = p2b + (((size_t)j1) << 8) + c2;
            const float* q2 = p2b + (((size_t)j2) << 8) + c2;
            float v[16];
#pragma unroll
            for (int g = 0; g < 4; ++g) {
                float4 x = *(const float4*)(q0 + g * 4);
                float4 y = *(const float4*)(q1 + g * 4);
                float4 z = *(const float4*)(q2 + g * 4);
                v[g * 4 + 0] = fmaf(wa, x.x, fmaf(wb, y.x, wc * z.x));
                v[g * 4 + 1] = fmaf(wa, x.y, fmaf(wb, y.y, wc * z.y));
                v[g * 4 + 2] = fmaf(wa, x.z, fmaf(wb, y.z, wc * z.z));
                v[g * 4 + 3] = fmaf(wa, x.w, fmaf(wb, y.w, wc * z.w));
            }
            pa0 = make_uint4(pk2(v[0], v[1]), pk2(v[2], v[3]), pk2(v[4], v[5]), pk2(v[6], v[7]));
            pa1 = make_uint4(pk2(v[8], v[9]), pk2(v[10], v[11]), pk2(v[12], v[13]), pk2(v[14], v[15]));
        }
        // ---- B bf16 direct copy (w1b is [256][384] row-major = B^T)
        const unsigned short* bsrc = w1b + (size_t)(col0 + r) * 384 + kc * 32 + half * 16;
        const uint4 qb0 = *(const uint4*)bsrc;
        const uint4 qb1 = *(const uint4*)(bsrc + 8);

        __syncthreads();   // WAR: previous iteration's frag reads complete
        *(uint4*)&As[r * LDB + half * 16] = pa0;
        *(uint4*)&As[r * LDB + half * 16 + 8] = pa1;
        *(uint4*)&Bs[r * LDB + half * 16] = qb0;
        *(uint4*)&Bs[r * LDB + half * 16 + 8] = qb1;
        __syncthreads();

        short8 af[2][2], bfv[2][2];
#pragma unroll
        for (int mt = 0; mt < 2; ++mt)
#pragma unroll
            for (int ks = 0; ks < 2; ++ks)
                af[mt][ks] = *(const short8*)&As[(wm + mt * 32 + ln) * LDB + ks * 16 + hk * 8];
#pragma unroll
        for (int nt = 0; nt < 2; ++nt)
#pragma unroll
            for (int ks = 0; ks < 2; ++ks)
                bfv[nt][ks] = *(const short8*)&Bs[(wn + nt * 32 + ln) * LDB + ks * 16 + hk * 8];
#pragma unroll
        for (int mt = 0; mt < 2; ++mt)
#pragma unroll
            for (int nt = 0; nt < 2; ++nt)
#pragma unroll
                for (int ks = 0; ks < 2; ++ks)
                    acc[mt][nt] = __builtin_amdgcn_mfma_f32_32x32x16_bf16(
                        af[mt][ks], bfv[nt][ks], acc[mt][nt], 0, 0, 0);
    }

    // ---- epilogue: bias, stats, store fp32 h1
    float biasv[2];
#pragma unroll
    for (int nt = 0; nt < 2; ++nt) biasv[nt] = b1p[col0 + wn + nt * 32 + ln];
#pragma unroll
    for (int mt = 0; mt < 2; ++mt) {
#pragma unroll
        for (int nt = 0; nt < 2; ++nt) {
            const int col = col0 + wn + nt * 32 + ln;
            float ps = 0.f, pq = 0.f;
#pragma unroll
            for (int e = 0; e < 16; ++e) {
                const int rl = wm + mt * 32 + (e & 3) + ((e >> 2) << 3) + (hk << 2);
                const float o = acc[mt][nt][e] + biasv[nt];
                ps += o;
                pq = fmaf(o, o, pq);
                h1[(((size_t)(row0 + rl)) << 8) + col] = o;
            }
            atomicAdd(&sSum[wn + nt * 32 + ln], ps);
            atomicAdd(&sSq[wn + nt * 32 + ln], pq);
        }
    }
    __syncthreads();
    if (tid < 128) {
        atomicAdd(&st1[col0 + tid], sSum[tid]);
        atomicAdd(&st1[256 + col0 + tid], sSq[tid]);
    }
}

// ---------------------------------------------------------------- BN coef prep
__global__ void k_bnprep(const float* __restrict__ st, const float* __restrict__ g,
                         const float* __restrict__ be, float* __restrict__ bn,
                         int C, float invM) {
    int c = blockIdx.x * blockDim.x + threadIdx.x;
    if (c < C) {
        float mean = st[c] * invM;
        float var = st[C + c] * invM - mean * mean;
        float a = g[c] / sqrtf(var + 1e-5f);
        bn[c] = a;
        bn[C + c] = fmaf(-mean, a, be[c]);
    }
}

// ---------------------------------------------------------------- GEMM2: MFMA bf16, BN1+ReLU fused, stats2
__global__ __launch_bounds__(256) void k_gemm2(const float* __restrict__ h1,
                                               const unsigned short* __restrict__ w2b,
                                               const float* __restrict__ b2p,
                                               const float* __restrict__ bn1,
                                               float* __restrict__ h2,
                                               float* __restrict__ st2) {
    __shared__ __align__(16) unsigned short As[128 * LDB];
    __shared__ __align__(16) unsigned short Bs[128 * LDB];
    __shared__ float sBNa[256], sBNb[256];
    __shared__ float sSum[128], sSq[128];

    const int tid = threadIdx.x;
    const int row0 = blockIdx.x * 128;

    sBNa[tid] = bn1[tid];
    sBNb[tid] = bn1[256 + tid];
    if (tid < 128) { sSum[tid] = 0.f; sSq[tid] = 0.f; }

    const int wave = tid >> 6, lane = tid & 63;
    const int ln = lane & 31, hk = lane >> 5;
    const int wm = (wave & 1) << 6, wn = (wave >> 1) << 6;
    const int r = tid >> 1, half = tid & 1;

    f32x16 acc[2][2];
#pragma unroll
    for (int mt = 0; mt < 2; ++mt)
#pragma unroll
        for (int nt = 0; nt < 2; ++nt)
#pragma unroll
            for (int e = 0; e < 16; ++e) acc[mt][nt][e] = 0.f;

    __syncthreads();   // sBN visible

    for (int kc = 0; kc < 8; ++kc) {
        const int k0 = kc * 32 + half * 16;
        const float* src = h1 + (((size_t)(row0 + r)) << 8) + k0;
        float v[16];
#pragma unroll
        for (int g = 0; g < 4; ++g) {
            float4 x = *(const float4*)(src + g * 4);
            v[g * 4 + 0] = fmaxf(fmaf(sBNa[k0 + g * 4 + 0], x.x, sBNb[k0 + g * 4 + 0]), 0.f);
            v[g * 4 + 1] = fmaxf(fmaf(sBNa[k0 + g * 4 + 1], x.y, sBNb[k0 + g * 4 + 1]), 0.f);
            v[g * 4 + 2] = fmaxf(fmaf(sBNa[k0 + g * 4 + 2], x.z, sBNb[k0 + g * 4 + 2]), 0.f);
            v[g * 4 + 3] = fmaxf(fmaf(sBNa[k0 + g * 4 + 3], x.w, sBNb[k0 + g * 4 + 3]), 0.f);
        }
        uint4 pa0 = make_uint4(pk2(v[0], v[1]), pk2(v[2], v[3]), pk2(v[4], v[5]), pk2(v[6], v[7]));
        uint4 pa1 = make_uint4(pk2(v[8], v[9]), pk2(v[10], v[11]), pk2(v[12], v[13]), pk2(v[14], v[15]));
        const unsigned short* bsrc = w2b + (size_t)r * 256 + k0;
        const uint4 qb0 = *(const uint4*)bsrc;
        const uint4 qb1 = *(const uint4*)(bsrc + 8);

        __syncthreads();
        *(uint4*)&As[r * LDB + half * 16] = pa0;
        *(uint4*)&As[r * LDB + half * 16 + 8] = pa1;
        *(uint4*)&Bs[r * LDB + half * 16] = qb0;
        *(uint4*)&Bs[r * LDB + half * 16 + 8] = qb1;
        __syncthreads();

        short8 af[2][2], bfv[2][2];
#pragma unroll
        for (int mt = 0; mt < 2; ++mt)
#pragma unroll
            for (int ks = 0; ks < 2; ++ks)
                af[mt][ks] = *(const short8*)&As[(wm + mt * 32 + ln) * LDB + ks * 16 + hk * 8];
#pragma unroll
        for (int nt = 0; nt < 2; ++nt)
#pragma unroll
            for (int ks = 0; ks < 2; ++ks)
                bfv[nt][ks] = *(const short8*)&Bs[(wn + nt * 32 + ln) * LDB + ks * 16 + hk * 8];
#pragma unroll
        for (int mt = 0; mt < 2; ++mt)
#pragma unroll
            for (int nt = 0; nt < 2; ++nt)
#pragma unroll
                for (int ks = 0; ks < 2; ++ks)
                    acc[mt][nt] = __builtin_amdgcn_mfma_f32_32x32x16_bf16(
                        af[mt][ks], bfv[nt][ks], acc[mt][nt], 0, 0, 0);
    }

    float biasv[2];
#pragma unroll
    for (int nt = 0; nt < 2; ++nt) biasv[nt] = b2p[wn + nt * 32 + ln];
#pragma unroll
    for (int mt = 0; mt < 2; ++mt) {
#pragma unroll
        for (int nt = 0; nt < 2; ++nt) {
            const int col = wn + nt * 32 + ln;
            float ps = 0.f, pq = 0.f;
#pragma unroll
            for (int e = 0; e < 16; ++e) {
                const int rl = wm + mt * 32 + (e & 3) + ((e >> 2) << 3) + (hk << 2);
                const float o = acc[mt][nt][e] + biasv[nt];
                ps += o;
                pq = fmaf(o, o, pq);
                h2[(((size_t)(row0 + rl)) << 7) + col] = o;
            }
            atomicAdd(&sSum[col], ps);
            atomicAdd(&sSq[col], pq);
        }
    }
    __syncthreads();
    if (tid < 128) {
        atomicAdd(&st2[tid], sSum[tid]);
        atomicAdd(&st2[128 + tid], sSq[tid]);
    }
}

// ---------------------------------------------------------------- pool pass
__global__ __launch_bounds__(256) void k_pool(const float* __restrict__ h2,
                                              const float* __restrict__ bn2,
                                              float* __restrict__ psum,
                                              int* __restrict__ pmax) {
    const int b = blockIdx.y;
    const int n0 = blockIdx.x * 256;
    const int tid = threadIdx.x;
    const int c = tid & 127, rh = tid >> 7;
    const float a = bn2[c], bc = bn2[128 + c];
    const float* base = h2 + (((size_t)b * NN + n0 + rh) << 7) + c;
    float s = 0.f, m = 0.f;
    for (int i = 0; i < 128; ++i) {
        float v = base[(size_t)i * 256];
        float x = fmaxf(fmaf(a, v, bc), 0.f);
        s += x;
        m = fmaxf(m, x);
    }
    __shared__ float rs[256];
    __shared__ float rm[256];
    rs[tid] = s; rm[tid] = m;
    __syncthreads();
    if (tid < 128) {
        float ts = rs[tid] + rs[tid + 128];
        float tm = fmaxf(rm[tid], rm[tid + 128]);
        atomicAdd(&psum[b * 128 + c], ts);
        atomicMax(&pmax[b * 128 + c], __float_as_int(tm));
    }
}

// ---------------------------------------------------------------- SE attention
__global__ __launch_bounds__(1024) void k_attn(const float* __restrict__ psum,
                                               const int* __restrict__ pmax,
                                               const float* __restrict__ fa1,
                                               const float* __restrict__ fa2,
                                               const float* __restrict__ bn2,
                                               float* __restrict__ sa,
                                               float* __restrict__ sb) {
    __shared__ float tS[128];
    const int tid = threadIdx.x;
    if (tid < 128) {
        const int b = tid >> 4, j = tid & 15;
        float da = 0.f, dm = 0.f;
        for (int cc = 0; cc < 128; ++cc) {
            float f = fa1[j * 128 + cc];
            da = fmaf(psum[b * 128 + cc] * (1.0f / 16384.0f), f, da);
            dm = fmaf(__int_as_float(pmax[b * 128 + cc]), f, dm);
        }
        tS[tid] = fmaxf(da, 0.f) + fmaxf(dm, 0.f);
    }
    __syncthreads();
    const int b = tid >> 7, c = tid & 127;
    float s = 0.f;
#pragma unroll
    for (int j = 0; j < 16; ++j) s = fmaf(tS[b * 16 + j], fa2[c * 16 + j], s);
    const float sc = 1.f / (1.f + expf(-s));
    sa[b * 128 + c] = bn2[c] * sc;
    sb[b * 128 + c] = bn2[128 + c] * sc;
}

// ---------------------------------------------------------------- final
__global__ void k_final(const float* __restrict__ h2, const float* __restrict__ sa,
                        const float* __restrict__ sb, float* __restrict__ out) {
    const size_t i = (size_t)blockIdx.x * blockDim.x + threadIdx.x;
    const int c4 = (int)(i & 31);
    const size_t row = i >> 5;
    const int b = (int)(row >> 14);
    float4 h = ((const float4*)h2)[i];
    float4 A = ((const float4*)sa)[(b << 5) + c4];
    float4 Bv = ((const float4*)sb)[(b << 5) + c4];
    float4 o;
    o.x = fmaxf(fmaf(A.x, h.x, Bv.x), 0.f);
    o.y = fmaxf(fmaf(A.y, h.y, Bv.y), 0.f);
    o.z = fmaxf(fmaf(A.z, h.z, Bv.z), 0.f);
    o.w = fmaxf(fmaf(A.w, h.w, Bv.w), 0.f);
    ((float4*)out)[i] = o;
}

// ---------------------------------------------------------------- launch
extern "C" void kernel_launch(void* const* d_in, const int* in_sizes, int n_in,
                              void* d_out, int out_size, void* d_ws, size_t ws_size,
                              hipStream_t stream) {
    const float* xyz1 = (const float*)d_in[0];
    const float* xyz2 = (const float*)d_in[1];
    const float* p1   = (const float*)d_in[2];
    const float* p2   = (const float*)d_in[3];
    const float* w1   = (const float*)d_in[4];
    const float* b1   = (const float*)d_in[5];
    const float* g1   = (const float*)d_in[6];
    const float* be1  = (const float*)d_in[7];
    const float* w2   = (const float*)d_in[8];
    const float* b2   = (const float*)d_in[9];
    const float* g2   = (const float*)d_in[10];
    const float* be2  = (const float*)d_in[11];
    const float* fa1  = (const float*)d_in[12];
    const float* fa2  = (const float*)d_in[13];
    float* out = (float*)d_out;

    char* ws = (char*)d_ws;
    int*   idx  = (int*)ws;                                   // 393216 ints
    float* wgt  = (float*)(ws + 1572864);                     // 393216 floats
    float* h1   = (float*)(ws + 3145728);                     // 134 MB fp32
    float* h2   = (float*)(ws + 137363456);                   // 67 MB fp32
    float* st1  = (float*)(ws + 204472320);                   // 512
    float* bn1  = st1 + 512;                                  // 512
    float* st2  = bn1 + 512;                                  // 256
    float* bn2  = st2 + 256;                                  // 256
    float* psum = bn2 + 256;                                  // 1024
    int*   pmax = (int*)(psum + 1024);                        // 1024
    float* sa   = (float*)(pmax + 1024);                      // 1024
    float* sb   = sa + 1024;                                  // 1024
    unsigned short* w1b = (unsigned short*)(sb + 1024);       // 98304 bf16
    unsigned short* w2b = w1b + 98304;                        // 32768 bf16

    k_init<<<1, 1024, 0, stream>>>(st1, st2, psum, pmax);
    k_wprep<<<(H1 * 384 + 255) / 256, 256, 0, stream>>>(w1, w2, w1b, w2b);
    k_knn<<<dim3(NN / 64, BB), 256, 0, stream>>>(xyz1, xyz2, idx, wgt);
    k_gemm1<<<dim3(MM / 128, 2), 256, 0, stream>>>(p1, p2, idx, wgt, w1b, b1, h1, st1);
    k_bnprep<<<1, 256, 0, stream>>>(st1, g1, be1, bn1, 256, 1.0f / (float)MM);
    k_gemm2<<<dim3(MM / 128, 1), 256, 0, stream>>>(h1, w2b, b2, bn1, h2, st2);
    k_bnprep<<<1, 128, 0, stream>>>(st2, g2, be2, bn2, 128, 1.0f / (float)MM);
    k_pool<<<dim3(NN / 256, BB), 256, 0, stream>>>(h2, bn2, psum, pmax);
    k_attn<<<1, 1024, 0, stream>>>(psum, pmax, fa1, fa2, bn2, sa, sb);
    k_final<<<(MM * H2 / 4) / 256, 256, 0, stream>>>(h2, sa, sb, out);
}

// Round 5
// 447.632 us; speedup vs baseline: 1.9981x; 1.1323x over previous
//
#include <hip/hip_runtime.h>
#include <math.h>

// Problem constants (fixed by setup_inputs)
constexpr int BB = 8;
constexpr int NN = 16384;
constexpr int SS = 2048;
constexpr int D2 = 256;
constexpr int H1 = 256;
constexpr int H2 = 128;
constexpr int MM = BB * NN;   // 131072 rows
constexpr int LDB = 40;       // LDS leading dim (bf16 elems): 80 B, 16B-aligned

typedef __attribute__((ext_vector_type(8))) short short8;    // bf16x8 frag (4 VGPRs)
typedef __attribute__((ext_vector_type(16))) float f32x16;   // 32x32 accumulator

__device__ __forceinline__ unsigned short f2b(float f) {     // fp32 -> bf16 RNE
    union { float f; unsigned u; } v; v.f = f;
    unsigned r = v.u + 0x7FFFu + ((v.u >> 16) & 1u);
    return (unsigned short)(r >> 16);
}
__device__ __forceinline__ unsigned pk2(float lo, float hi) {
    return (unsigned)f2b(lo) | ((unsigned)f2b(hi) << 16);
}
__device__ __forceinline__ float b2f_lo(unsigned p) { return __uint_as_float(p << 16); }
__device__ __forceinline__ float b2f_hi(unsigned p) { return __uint_as_float(p & 0xFFFF0000u); }

// ---------------------------------------------------------------- init
__global__ void k_init(float* __restrict__ st1, float* __restrict__ st2,
                       float* __restrict__ psum, int* __restrict__ pmax) {
    int t = threadIdx.x;
    if (t < 512) st1[t] = 0.f;
    if (t < 256) st2[t] = 0.f;
    if (t < 1024) { psum[t] = 0.f; pmax[t] = 0; }
}

// ---------------------------------------------------------------- weight fp32->bf16 prep
__global__ void k_wprep(const float* __restrict__ w1, const float* __restrict__ w2,
                        unsigned short* __restrict__ w1b, unsigned short* __restrict__ w2b) {
    int i = blockIdx.x * 256 + threadIdx.x;
    if (i < H1 * 384) w1b[i] = f2b(w1[i]);
    if (i < H2 * 256) w2b[i] = f2b(w2[i]);
}

// ---------------------------------------------------------------- 3-NN
// fp32 exact-form scan, packed uint keys (branchless top-5/chunk),
// 4-way S-split per query, fp64 refine of 20 candidates -> exact top-3.
__global__ __launch_bounds__(256) void k_knn(const float* __restrict__ xyz1,
                                             const float* __restrict__ xyz2,
                                             int* __restrict__ idx,
                                             float* __restrict__ wgt) {
    __shared__ float sx[SS], sy[SS], sz[SS];      // 24 KB
    __shared__ unsigned cand[64][20];             // 5 KB
    const int b = blockIdx.y;
    const int tid = threadIdx.x;
    const int ql = tid & 63;
    const int chunk = tid >> 6;
    const int n = blockIdx.x * 64 + ql;

    const float* xz2 = xyz2 + (size_t)b * SS * 3;
    for (int s = tid; s < SS; s += 256) {
        sx[s] = xz2[s * 3 + 0];
        sy[s] = xz2[s * 3 + 1];
        sz[s] = xz2[s * 3 + 2];
    }
    __syncthreads();

    const float* q = xyz1 + ((size_t)b * NN + n) * 3;
    const float qx = q[0], qy = q[1], qz = q[2];

    unsigned k0 = 0xFFFFFFFFu, k1 = 0xFFFFFFFFu, k2 = 0xFFFFFFFFu,
             k3 = 0xFFFFFFFFu, k4 = 0xFFFFFFFFu;
    const int s0 = chunk * 512;
#pragma unroll 4
    for (int j = 0; j < 512; ++j) {
        const int s = s0 + j;
        const float dx = qx - sx[s];
        const float dy = qy - sy[s];
        const float dz = qz - sz[s];
        const float d = fmaf(dx, dx, fmaf(dy, dy, dz * dz));
        const unsigned key = (__float_as_uint(d) & 0xFFFFFE00u) | (unsigned)j;
        const bool c0 = key < k0, c1 = key < k1, c2 = key < k2,
                   c3 = key < k3, c4 = key < k4;
        k4 = c4 ? (c3 ? k3 : key) : k4;
        k3 = c3 ? (c2 ? k2 : key) : k3;
        k2 = c2 ? (c1 ? k1 : key) : k2;
        k1 = c1 ? (c0 ? k0 : key) : k1;
        k0 = c0 ? key : k0;
    }
    unsigned* cq = cand[ql] + chunk * 5;
    cq[0] = k0; cq[1] = k1; cq[2] = k2; cq[3] = k3; cq[4] = k4;
    __syncthreads();

    if (tid < 64) {
        const double qxd = (double)qx, qyd = (double)qy, qzd = (double)qz;
        double t0 = 1e300, t1 = 1e300, t2 = 1e300;
        int i0 = 0, i1 = 0, i2 = 0;
#pragma unroll
        for (int ch = 0; ch < 4; ++ch) {
#pragma unroll
            for (int t = 0; t < 5; ++t) {
                const int s = ch * 512 + (int)(cand[tid][ch * 5 + t] & 0x1FFu);
                const double dx = qxd - (double)sx[s];
                const double dy = qyd - (double)sy[s];
                const double dz = qzd - (double)sz[s];
                const double d = fma(dx, dx, fma(dy, dy, dz * dz));
                if (d < t2) {
                    if (d < t0)      { t2 = t1; i2 = i1; t1 = t0; i1 = i0; t0 = d; i0 = s; }
                    else if (d < t1) { t2 = t1; i2 = i1; t1 = d; i1 = s; }
                    else             { t2 = d; i2 = s; }
                }
            }
        }
        const double r0 = 1.0 / (t0 + 1e-8);
        const double r1 = 1.0 / (t1 + 1e-8);
        const double r2 = 1.0 / (t2 + 1e-8);
        const double inv = 1.0 / (r0 + r1 + r2);
        const size_t o = ((size_t)b * NN + n) * 3;
        idx[o + 0] = i0; idx[o + 1] = i1; idx[o + 2] = i2;
        wgt[o + 0] = (float)(r0 * inv);
        wgt[o + 1] = (float)(r1 * inv);
        wgt[o + 2] = (float)(r2 * inv);
    }
}

// ---------------------------------------------------------------- GEMM1: 128x256 tile, MFMA bf16,
// fused interp+concat, register-prefetch pipeline, bf16 h1 out, stats1
__global__ __launch_bounds__(256, 2) void k_gemm1(const float* __restrict__ p1,
                                                  const float* __restrict__ p2,
                                                  const int* __restrict__ idx,
                                                  const float* __restrict__ wgt,
                                                  const unsigned short* __restrict__ w1b,
                                                  const float* __restrict__ b1p,
                                                  unsigned short* __restrict__ h1b,
                                                  float* __restrict__ st1) {
    __shared__ __align__(16) unsigned short As[128 * LDB];   // 10 KB
    __shared__ __align__(16) unsigned short Bs[256 * LDB];   // 20 KB
    __shared__ float sSum[256], sSq[256];

    const int tid = threadIdx.x;
    const int row0 = blockIdx.x * 128;
    const int b = row0 >> 14;
    const float* p2b = p2 + (size_t)b * (SS * D2);

    sSum[tid] = 0.f; sSq[tid] = 0.f;

    const int wave = tid >> 6, lane = tid & 63;
    const int ln = lane & 31, hk = lane >> 5;
    const int wm = (wave & 1) << 6;    // 0/64 row offset
    const int wn = (wave >> 1) << 7;   // 0/128 col offset
    const int r = tid >> 1, half = tid & 1;

    // per-row neighbor info (constant over kc)
    const size_t o3 = (size_t)(row0 + r) * 3;
    const int j0 = idx[o3], j1 = idx[o3 + 1], j2 = idx[o3 + 2];
    const float wa = wgt[o3], wb = wgt[o3 + 1], wc = wgt[o3 + 2];
    const float* g0 = p2b + ((size_t)j0 << 8);
    const float* g1 = p2b + ((size_t)j1 << 8);
    const float* g2 = p2b + ((size_t)j2 << 8);

    f32x16 acc[2][4];
#pragma unroll
    for (int mt = 0; mt < 2; ++mt)
#pragma unroll
        for (int nt = 0; nt < 4; ++nt)
#pragma unroll
            for (int e = 0; e < 16; ++e) acc[mt][nt][e] = 0.f;

    float4 ra[12];     // raw A prefetch (gather path uses all 12)
    uint4 rb[4];       // raw B prefetch (w1b row tid, 32 k)

    auto prefetch = [&](int kc) {
        const unsigned short* bsrc = w1b + (size_t)tid * 384 + kc * 32;
        rb[0] = *(const uint4*)(bsrc);
        rb[1] = *(const uint4*)(bsrc + 8);
        rb[2] = *(const uint4*)(bsrc + 16);
        rb[3] = *(const uint4*)(bsrc + 24);
        if (kc < 4) {
            const float* src = p1 + (((size_t)(row0 + r)) << 7) + kc * 32 + half * 16;
            ra[0] = *(const float4*)(src);
            ra[1] = *(const float4*)(src + 4);
            ra[2] = *(const float4*)(src + 8);
            ra[3] = *(const float4*)(src + 12);
        } else {
            const int c2 = kc * 32 - 128 + half * 16;
#pragma unroll
            for (int g = 0; g < 4; ++g) {
                ra[g]     = *(const float4*)(g0 + c2 + g * 4);
                ra[4 + g] = *(const float4*)(g1 + c2 + g * 4);
                ra[8 + g] = *(const float4*)(g2 + c2 + g * 4);
            }
        }
    };

    prefetch(0);

    for (int kc = 0; kc < 12; ++kc) {
        uint4 pa0, pa1;
        if (kc < 4) {
            pa0 = make_uint4(pk2(ra[0].x, ra[0].y), pk2(ra[0].z, ra[0].w),
                             pk2(ra[1].x, ra[1].y), pk2(ra[1].z, ra[1].w));
            pa1 = make_uint4(pk2(ra[2].x, ra[2].y), pk2(ra[2].z, ra[2].w),
                             pk2(ra[3].x, ra[3].y), pk2(ra[3].z, ra[3].w));
        } else {
            float v[16];
#pragma unroll
            for (int g = 0; g < 4; ++g) {
                v[g * 4 + 0] = fmaf(wa, ra[g].x, fmaf(wb, ra[4 + g].x, wc * ra[8 + g].x));
                v[g * 4 + 1] = fmaf(wa, ra[g].y, fmaf(wb, ra[4 + g].y, wc * ra[8 + g].y));
                v[g * 4 + 2] = fmaf(wa, ra[g].z, fmaf(wb, ra[4 + g].z, wc * ra[8 + g].z));
                v[g * 4 + 3] = fmaf(wa, ra[g].w, fmaf(wb, ra[4 + g].w, wc * ra[8 + g].w));
            }
            pa0 = make_uint4(pk2(v[0], v[1]), pk2(v[2], v[3]), pk2(v[4], v[5]), pk2(v[6], v[7]));
            pa1 = make_uint4(pk2(v[8], v[9]), pk2(v[10], v[11]), pk2(v[12], v[13]), pk2(v[14], v[15]));
        }
        const uint4 wb0 = rb[0], wb1 = rb[1], wb2 = rb[2], wb3 = rb[3];

        __syncthreads();   // WAR: prior iteration's frag reads complete
        *(uint4*)&As[r * LDB + half * 16] = pa0;
        *(uint4*)&As[r * LDB + half * 16 + 8] = pa1;
        *(uint4*)&Bs[tid * LDB + 0]  = wb0;
        *(uint4*)&Bs[tid * LDB + 8]  = wb1;
        *(uint4*)&Bs[tid * LDB + 16] = wb2;
        *(uint4*)&Bs[tid * LDB + 24] = wb3;
        __syncthreads();

        if (kc < 11) prefetch(kc + 1);   // loads in flight during frags+MFMA

        short8 af[2][2], bfv[4][2];
#pragma unroll
        for (int mt = 0; mt < 2; ++mt)
#pragma unroll
            for (int ks = 0; ks < 2; ++ks)
                af[mt][ks] = *(const short8*)&As[(wm + mt * 32 + ln) * LDB + ks * 16 + hk * 8];
#pragma unroll
        for (int nt = 0; nt < 4; ++nt)
#pragma unroll
            for (int ks = 0; ks < 2; ++ks)
                bfv[nt][ks] = *(const short8*)&Bs[(wn + nt * 32 + ln) * LDB + ks * 16 + hk * 8];
#pragma unroll
        for (int mt = 0; mt < 2; ++mt)
#pragma unroll
            for (int nt = 0; nt < 4; ++nt)
#pragma unroll
                for (int ks = 0; ks < 2; ++ks)
                    acc[mt][nt] = __builtin_amdgcn_mfma_f32_32x32x16_bf16(
                        af[mt][ks], bfv[nt][ks], acc[mt][nt], 0, 0, 0);
    }

    // ---- epilogue: bias, stats, bf16 h1 store
#pragma unroll
    for (int nt = 0; nt < 4; ++nt) {
        const int col = wn + nt * 32 + ln;
        const float bias = b1p[col];
        float ps = 0.f, pq = 0.f;
#pragma unroll
        for (int mt = 0; mt < 2; ++mt) {
#pragma unroll
            for (int e = 0; e < 16; ++e) {
                const int rl = wm + mt * 32 + (e & 3) + ((e >> 2) << 3) + (hk << 2);
                const float o = acc[mt][nt][e] + bias;
                ps += o;
                pq = fmaf(o, o, pq);
                h1b[(((size_t)(row0 + rl)) << 8) + col] = f2b(o);
            }
        }
        atomicAdd(&sSum[col], ps);
        atomicAdd(&sSq[col], pq);
    }
    __syncthreads();
    atomicAdd(&st1[tid], sSum[tid]);
    atomicAdd(&st1[256 + tid], sSq[tid]);
}

// ---------------------------------------------------------------- BN coef prep
__global__ void k_bnprep(const float* __restrict__ st, const float* __restrict__ g,
                         const float* __restrict__ be, float* __restrict__ bn,
                         int C, float invM) {
    int c = blockIdx.x * blockDim.x + threadIdx.x;
    if (c < C) {
        float mean = st[c] * invM;
        float var = st[C + c] * invM - mean * mean;
        float a = g[c] / sqrtf(var + 1e-5f);
        bn[c] = a;
        bn[C + c] = fmaf(-mean, a, be[c]);
    }
}

// ---------------------------------------------------------------- GEMM2: MFMA bf16, BN1+ReLU fused,
// register-prefetch pipeline, bf16 in/out, stats2
__global__ __launch_bounds__(256) void k_gemm2(const unsigned short* __restrict__ h1b,
                                               const unsigned short* __restrict__ w2b,
                                               const float* __restrict__ b2p,
                                               const float* __restrict__ bn1,
                                               unsigned short* __restrict__ h2b,
                                               float* __restrict__ st2) {
    __shared__ __align__(16) unsigned short As[128 * LDB];
    __shared__ __align__(16) unsigned short Bs[128 * LDB];
    __shared__ float sBNa[256], sBNb[256];
    __shared__ float sSum[128], sSq[128];

    const int tid = threadIdx.x;
    const int row0 = blockIdx.x * 128;

    sBNa[tid] = bn1[tid];
    sBNb[tid] = bn1[256 + tid];
    if (tid < 128) { sSum[tid] = 0.f; sSq[tid] = 0.f; }

    const int wave = tid >> 6, lane = tid & 63;
    const int ln = lane & 31, hk = lane >> 5;
    const int wm = (wave & 1) << 6, wn = (wave >> 1) << 6;
    const int r = tid >> 1, half = tid & 1;

    f32x16 acc[2][2];
#pragma unroll
    for (int mt = 0; mt < 2; ++mt)
#pragma unroll
        for (int nt = 0; nt < 2; ++nt)
#pragma unroll
            for (int e = 0; e < 16; ++e) acc[mt][nt][e] = 0.f;

    uint4 rA0, rA1, rB0, rB1;
    auto prefetch = [&](int kc) {
        const unsigned short* asrc = h1b + (size_t)(row0 + r) * 256 + kc * 32 + half * 16;
        rA0 = *(const uint4*)asrc;
        rA1 = *(const uint4*)(asrc + 8);
        const unsigned short* bsrc = w2b + (size_t)r * 256 + kc * 32 + half * 16;
        rB0 = *(const uint4*)bsrc;
        rB1 = *(const uint4*)(bsrc + 8);
    };

    prefetch(0);
    __syncthreads();   // sBN visible

    for (int kc = 0; kc < 8; ++kc) {
        const int k0 = kc * 32 + half * 16;
        unsigned pw[8] = {rA0.x, rA0.y, rA0.z, rA0.w, rA1.x, rA1.y, rA1.z, rA1.w};
        unsigned po[8];
#pragma unroll
        for (int gi = 0; gi < 8; ++gi) {
            float lo = b2f_lo(pw[gi]);
            float hi = b2f_hi(pw[gi]);
            lo = fmaxf(fmaf(sBNa[k0 + 2 * gi], lo, sBNb[k0 + 2 * gi]), 0.f);
            hi = fmaxf(fmaf(sBNa[k0 + 2 * gi + 1], hi, sBNb[k0 + 2 * gi + 1]), 0.f);
            po[gi] = pk2(lo, hi);
        }
        const uint4 pa0 = make_uint4(po[0], po[1], po[2], po[3]);
        const uint4 pa1 = make_uint4(po[4], po[5], po[6], po[7]);
        const uint4 qb0 = rB0, qb1 = rB1;

        __syncthreads();
        *(uint4*)&As[r * LDB + half * 16] = pa0;
        *(uint4*)&As[r * LDB + half * 16 + 8] = pa1;
        *(uint4*)&Bs[r * LDB + half * 16] = qb0;
        *(uint4*)&Bs[r * LDB + half * 16 + 8] = qb1;
        __syncthreads();

        if (kc < 7) prefetch(kc + 1);

        short8 af[2][2], bfv[2][2];
#pragma unroll
        for (int mt = 0; mt < 2; ++mt)
#pragma unroll
            for (int ks = 0; ks < 2; ++ks)
                af[mt][ks] = *(const short8*)&As[(wm + mt * 32 + ln) * LDB + ks * 16 + hk * 8];
#pragma unroll
        for (int nt = 0; nt < 2; ++nt)
#pragma unroll
            for (int ks = 0; ks < 2; ++ks)
                bfv[nt][ks] = *(const short8*)&Bs[(wn + nt * 32 + ln) * LDB + ks * 16 + hk * 8];
#pragma unroll
        for (int mt = 0; mt < 2; ++mt)
#pragma unroll
            for (int nt = 0; nt < 2; ++nt)
#pragma unroll
                for (int ks = 0; ks < 2; ++ks)
                    acc[mt][nt] = __builtin_amdgcn_mfma_f32_32x32x16_bf16(
                        af[mt][ks], bfv[nt][ks], acc[mt][nt], 0, 0, 0);
    }

#pragma unroll
    for (int nt = 0; nt < 2; ++nt) {
        const int col = wn + nt * 32 + ln;
        const float bias = b2p[col];
        float ps = 0.f, pq = 0.f;
#pragma unroll
        for (int mt = 0; mt < 2; ++mt) {
#pragma unroll
            for (int e = 0; e < 16; ++e) {
                const int rl = wm + mt * 32 + (e & 3) + ((e >> 2) << 3) + (hk << 2);
                const float o = acc[mt][nt][e] + bias;
                ps += o;
                pq = fmaf(o, o, pq);
                h2b[(((size_t)(row0 + rl)) << 7) + col] = f2b(o);
            }
        }
        atomicAdd(&sSum[col], ps);
        atomicAdd(&sSq[col], pq);
    }
    __syncthreads();
    if (tid < 128) {
        atomicAdd(&st2[tid], sSum[tid]);
        atomicAdd(&st2[128 + tid], sSq[tid]);
    }
}

// ---------------------------------------------------------------- pool pass (bf16 h2)
__global__ __launch_bounds__(256) void k_pool(const unsigned short* __restrict__ h2b,
                                              const float* __restrict__ bn2,
                                              float* __restrict__ psum,
                                              int* __restrict__ pmax) {
    const int b = blockIdx.y;
    const int n0 = blockIdx.x * 256;
    const int tid = threadIdx.x;
    const int c = tid & 127, rh = tid >> 7;
    const float a = bn2[c], bc = bn2[128 + c];
    const unsigned short* base = h2b + (((size_t)b * NN + n0 + rh) << 7) + c;
    float s = 0.f, m = 0.f;
    for (int i = 0; i < 128; ++i) {
        float v = __uint_as_float((unsigned)base[(size_t)i * 256] << 16);
        float x = fmaxf(fmaf(a, v, bc), 0.f);
        s += x;
        m = fmaxf(m, x);
    }
    __shared__ float rs[256];
    __shared__ float rm[256];
    rs[tid] = s; rm[tid] = m;
    __syncthreads();
    if (tid < 128) {
        float ts = rs[tid] + rs[tid + 128];
        float tm = fmaxf(rm[tid], rm[tid + 128]);
        atomicAdd(&psum[b * 128 + c], ts);
        atomicMax(&pmax[b * 128 + c], __float_as_int(tm));
    }
}

// ---------------------------------------------------------------- SE attention
__global__ __launch_bounds__(1024) void k_attn(const float* __restrict__ psum,
                                               const int* __restrict__ pmax,
                                               const float* __restrict__ fa1,
                                               const float* __restrict__ fa2,
                                               const float* __restrict__ bn2,
                                               float* __restrict__ sa,
                                               float* __restrict__ sb) {
    __shared__ float tS[128];
    const int tid = threadIdx.x;
    if (tid < 128) {
        const int b = tid >> 4, j = tid & 15;
        float da = 0.f, dm = 0.f;
        for (int cc = 0; cc < 128; ++cc) {
            float f = fa1[j * 128 + cc];
            da = fmaf(psum[b * 128 + cc] * (1.0f / 16384.0f), f, da);
            dm = fmaf(__int_as_float(pmax[b * 128 + cc]), f, dm);
        }
        tS[tid] = fmaxf(da, 0.f) + fmaxf(dm, 0.f);
    }
    __syncthreads();
    const int b = tid >> 7, c = tid & 127;
    float s = 0.f;
#pragma unroll
    for (int j = 0; j < 16; ++j) s = fmaf(tS[b * 16 + j], fa2[c * 16 + j], s);
    const float sc = 1.f / (1.f + expf(-s));
    sa[b * 128 + c] = bn2[c] * sc;
    sb[b * 128 + c] = bn2[128 + c] * sc;
}

// ---------------------------------------------------------------- final (bf16 h2 -> fp32 out)
__global__ void k_final(const unsigned short* __restrict__ h2b, const float* __restrict__ sa,
                        const float* __restrict__ sb, float* __restrict__ out) {
    const size_t i = (size_t)blockIdx.x * blockDim.x + threadIdx.x;  // 8-elem group
    const int cg = (int)(i & 15) * 8;
    const size_t row = i >> 4;
    const int b = (int)(row >> 14);
    const uint4 h = *(const uint4*)(h2b + (row << 7) + cg);
    const float4 A0 = *(const float4*)&sa[b * 128 + cg];
    const float4 A1 = *(const float4*)&sa[b * 128 + cg + 4];
    const float4 B0 = *(const float4*)&sb[b * 128 + cg];
    const float4 B1 = *(const float4*)&sb[b * 128 + cg + 4];
    float4 o0, o1;
    o0.x = fmaxf(fmaf(A0.x, b2f_lo(h.x), B0.x), 0.f);
    o0.y = fmaxf(fmaf(A0.y, b2f_hi(h.x), B0.y), 0.f);
    o0.z = fmaxf(fmaf(A0.z, b2f_lo(h.y), B0.z), 0.f);
    o0.w = fmaxf(fmaf(A0.w, b2f_hi(h.y), B0.w), 0.f);
    o1.x = fmaxf(fmaf(A1.x, b2f_lo(h.z), B1.x), 0.f);
    o1.y = fmaxf(fmaf(A1.y, b2f_hi(h.z), B1.y), 0.f);
    o1.z = fmaxf(fmaf(A1.z, b2f_lo(h.w), B1.z), 0.f);
    o1.w = fmaxf(fmaf(A1.w, b2f_hi(h.w), B1.w), 0.f);
    *(float4*)(out + (row << 7) + cg) = o0;
    *(float4*)(out + (row << 7) + cg + 4) = o1;
}

// ---------------------------------------------------------------- launch
extern "C" void kernel_launch(void* const* d_in, const int* in_sizes, int n_in,
                              void* d_out, int out_size, void* d_ws, size_t ws_size,
                              hipStream_t stream) {
    const float* xyz1 = (const float*)d_in[0];
    const float* xyz2 = (const float*)d_in[1];
    const float* p1   = (const float*)d_in[2];
    const float* p2   = (const float*)d_in[3];
    const float* w1   = (const float*)d_in[4];
    const float* b1   = (const float*)d_in[5];
    const float* g1   = (const float*)d_in[6];
    const float* be1  = (const float*)d_in[7];
    const float* w2   = (const float*)d_in[8];
    const float* b2   = (const float*)d_in[9];
    const float* g2   = (const float*)d_in[10];
    const float* be2  = (const float*)d_in[11];
    const float* fa1  = (const float*)d_in[12];
    const float* fa2  = (const float*)d_in[13];
    float* out = (float*)d_out;

    char* ws = (char*)d_ws;
    int*   idx  = (int*)ws;                                   // 1.57 MB
    float* wgt  = (float*)(ws + 1572864);                     // 1.57 MB
    unsigned short* h1b = (unsigned short*)(ws + 3145728);    // 67 MB bf16
    unsigned short* h2b = (unsigned short*)(ws + 70254592);   // 33.5 MB bf16
    float* st1  = (float*)(ws + 103809024);                   // 512
    float* bn1  = st1 + 512;
    float* st2  = bn1 + 512;
    float* bn2  = st2 + 256;
    float* psum = bn2 + 256;
    int*   pmax = (int*)(psum + 1024);
    float* sa   = (float*)(pmax + 1024);
    float* sb   = sa + 1024;
    unsigned short* w1b = (unsigned short*)(sb + 1024);       // 98304 bf16
    unsigned short* w2b = w1b + 98304;                        // 32768 bf16

    k_init<<<1, 1024, 0, stream>>>(st1, st2, psum, pmax);
    k_wprep<<<(H1 * 384 + 255) / 256, 256, 0, stream>>>(w1, w2, w1b, w2b);
    k_knn<<<dim3(NN / 64, BB), 256, 0, stream>>>(xyz1, xyz2, idx, wgt);
    k_gemm1<<<MM / 128, 256, 0, stream>>>(p1, p2, idx, wgt, w1b, b1, h1b, st1);
    k_bnprep<<<1, 256, 0, stream>>>(st1, g1, be1, bn1, 256, 1.0f / (float)MM);
    k_gemm2<<<MM / 128, 256, 0, stream>>>(h1b, w2b, b2, bn1, h2b, st2);
    k_bnprep<<<1, 128, 0, stream>>>(st2, g2, be2, bn2, 128, 1.0f / (float)MM);
    k_pool<<<dim3(NN / 256, BB), 256, 0, stream>>>(h2b, bn2, psum, pmax);
    k_attn<<<1, 1024, 0, stream>>>(psum, pmax, fa1, fa2, bn2, sa, sb);
    k_final<<<(MM * H2 / 8) / 256, 256, 0, stream>>>(h2b, sa, sb, out);
}

// Round 7
// 417.271 us; speedup vs baseline: 2.1435x; 1.0728x over previous
//
#include <hip/hip_runtime.h>
#include <math.h>

// Problem constants (fixed by setup_inputs)
constexpr int BB = 8;
constexpr int NN = 16384;
constexpr int SS = 2048;
constexpr int D2 = 256;
constexpr int H1 = 256;
constexpr int H2 = 128;
constexpr int MM = BB * NN;   // 131072 rows
constexpr int LDB = 40;       // LDS leading dim (bf16 elems): 80 B, 16B-aligned

typedef __attribute__((ext_vector_type(8))) short short8;    // bf16x8 frag (4 VGPRs)
typedef __attribute__((ext_vector_type(16))) float f32x16;   // 32x32 accumulator

__device__ __forceinline__ unsigned short f2b(float f) {     // fp32 -> bf16 RNE
    union { float f; unsigned u; } v; v.f = f;
    unsigned r = v.u + 0x7FFFu + ((v.u >> 16) & 1u);
    return (unsigned short)(r >> 16);
}
__device__ __forceinline__ unsigned pk2(float lo, float hi) {
    return (unsigned)f2b(lo) | ((unsigned)f2b(hi) << 16);
}
__device__ __forceinline__ float b2f_lo(unsigned p) { return __uint_as_float(p << 16); }
__device__ __forceinline__ float b2f_hi(unsigned p) { return __uint_as_float(p & 0xFFFF0000u); }

// ---------------------------------------------------------------- init
__global__ void k_init(float* __restrict__ st1, float* __restrict__ st2,
                       float* __restrict__ psum, int* __restrict__ pmax) {
    int t = threadIdx.x;
    if (t < 512) st1[t] = 0.f;
    if (t < 256) st2[t] = 0.f;
    if (t < 1024) { psum[t] = 0.f; pmax[t] = 0; }
}

// ---------------------------------------------------------------- weight fp32->bf16 prep
__global__ void k_wprep(const float* __restrict__ w1, const float* __restrict__ w2,
                        unsigned short* __restrict__ w1b, unsigned short* __restrict__ w2b) {
    int i = blockIdx.x * 256 + threadIdx.x;
    if (i < H1 * 384) w1b[i] = f2b(w1[i]);
    if (i < H2 * 256) w2b[i] = f2b(w2[i]);
}

// ---------------------------------------------------------------- xyz2 -> float4 pack (for scalar loads)
__global__ void k_xyzprep(const float* __restrict__ xyz2, float4* __restrict__ xyz2p) {
    int i = blockIdx.x * 256 + threadIdx.x;   // 0 .. BB*SS-1
    if (i < BB * SS) {
        xyz2p[i] = make_float4(xyz2[i * 3], xyz2[i * 3 + 1], xyz2[i * 3 + 2], 0.f);
    }
}

// ---------------------------------------------------------------- 3-NN
// Wave-uniform candidate stream via scalar loads (no LDS staging),
// branchless top-4/chunk via v_min_u32/v_max_u32 bubble insert,
// 4-way S-split per query, fp64 refine of 16 candidates -> exact top-3.
__global__ __launch_bounds__(256) void k_knn(const float* __restrict__ xyz1,
                                             const float4* __restrict__ xyz2p,
                                             int* __restrict__ idx,
                                             float* __restrict__ wgt) {
    __shared__ unsigned cand[64][16];             // 4 KB: [query][chunk*4+t]
    const int b = blockIdx.y;
    const int tid = threadIdx.x;
    const int ql = tid & 63;                      // query-local
    const int n = blockIdx.x * 64 + ql;

    const float* q = xyz1 + ((size_t)b * NN + n) * 3;
    const float qx = q[0], qy = q[1], qz = q[2];

    // wave-uniform chunk base -> scalar loads through K$
    const int chunk = __builtin_amdgcn_readfirstlane(tid >> 6);   // 0..3
    const float4* cp = xyz2p + ((size_t)b << 11) + (chunk << 9);

    unsigned k0 = 0xFFFFFFFFu, k1 = 0xFFFFFFFFu, k2 = 0xFFFFFFFFu, k3 = 0xFFFFFFFFu;
#pragma unroll 4
    for (int j = 0; j < 512; ++j) {
        const float4 p = cp[j];
        const float dx = qx - p.x;
        const float dy = qy - p.y;
        const float dz = qz - p.z;
        const float d = fmaf(dx, dx, fmaf(dy, dy, dz * dz));
        const unsigned key = (__float_as_uint(d) & 0xFFFFFE00u) | (unsigned)j;
        // bubble insert into sorted {k0<=k1<=k2<=k3} with min/max chain (no vcc)
        unsigned m;
        m  = max(k0, key); k0 = min(k0, key);
        unsigned m2 = max(k1, m); k1 = min(k1, m);
        unsigned m3 = max(k2, m2); k2 = min(k2, m2);
        k3 = min(k3, m3);
    }
    unsigned* cq = cand[ql] + chunk * 4;
    cq[0] = k0; cq[1] = k1; cq[2] = k2; cq[3] = k3;
    __syncthreads();

    if (tid < 64) {
        const double qxd = (double)qx, qyd = (double)qy, qzd = (double)qz;
        double t0 = 1e300, t1 = 1e300, t2 = 1e300;
        int i0 = 0, i1 = 0, i2 = 0;
#pragma unroll
        for (int c = 0; c < 16; ++c) {
            const int s = ((c >> 2) << 9) + (int)(cand[tid][c] & 0x1FFu);
            const float4 p = xyz2p[((size_t)b << 11) + s];
            const double dx = qxd - (double)p.x;
            const double dy = qyd - (double)p.y;
            const double dz = qzd - (double)p.z;
            const double d = fma(dx, dx, fma(dy, dy, dz * dz));
            if (d < t2) {
                if (d < t0)      { t2 = t1; i2 = i1; t1 = t0; i1 = i0; t0 = d; i0 = s; }
                else if (d < t1) { t2 = t1; i2 = i1; t1 = d; i1 = s; }
                else             { t2 = d; i2 = s; }
            }
        }
        const double r0 = 1.0 / (t0 + 1e-8);
        const double r1 = 1.0 / (t1 + 1e-8);
        const double r2 = 1.0 / (t2 + 1e-8);
        const double inv = 1.0 / (r0 + r1 + r2);
        const size_t o = ((size_t)b * NN + n) * 3;
        idx[o + 0] = i0; idx[o + 1] = i1; idx[o + 2] = i2;
        wgt[o + 0] = (float)(r0 * inv);
        wgt[o + 1] = (float)(r1 * inv);
        wgt[o + 2] = (float)(r2 * inv);
    }
}

// ---------------------------------------------------------------- GEMM1: 128x256 tile, MFMA bf16,
// fused interp+concat, register-prefetch pipeline, bf16 h1 out, stats1
__global__ __launch_bounds__(256, 2) void k_gemm1(const float* __restrict__ p1,
                                                  const float* __restrict__ p2,
                                                  const int* __restrict__ idx,
                                                  const float* __restrict__ wgt,
                                                  const unsigned short* __restrict__ w1b,
                                                  const float* __restrict__ b1p,
                                                  unsigned short* __restrict__ h1b,
                                                  float* __restrict__ st1) {
    __shared__ __align__(16) unsigned short As[128 * LDB];   // 10 KB
    __shared__ __align__(16) unsigned short Bs[256 * LDB];   // 20 KB
    __shared__ float sSum[256], sSq[256];

    const int tid = threadIdx.x;
    const int row0 = blockIdx.x * 128;
    const int b = row0 >> 14;
    const float* p2b = p2 + (size_t)b * (SS * D2);

    sSum[tid] = 0.f; sSq[tid] = 0.f;

    const int wave = tid >> 6, lane = tid & 63;
    const int ln = lane & 31, hk = lane >> 5;
    const int wm = (wave & 1) << 6;    // 0/64 row offset
    const int wn = (wave >> 1) << 7;   // 0/128 col offset
    const int r = tid >> 1, half = tid & 1;

    // per-row neighbor info (constant over kc)
    const size_t o3 = (size_t)(row0 + r) * 3;
    const int j0 = idx[o3], j1 = idx[o3 + 1], j2 = idx[o3 + 2];
    const float wa = wgt[o3], wb = wgt[o3 + 1], wc = wgt[o3 + 2];
    const float* g0 = p2b + ((size_t)j0 << 8);
    const float* g1 = p2b + ((size_t)j1 << 8);
    const float* g2 = p2b + ((size_t)j2 << 8);

    f32x16 acc[2][4];
#pragma unroll
    for (int mt = 0; mt < 2; ++mt)
#pragma unroll
        for (int nt = 0; nt < 4; ++nt)
#pragma unroll
            for (int e = 0; e < 16; ++e) acc[mt][nt][e] = 0.f;

    float4 ra[12];     // raw A prefetch (gather path uses all 12)
    uint4 rb[4];       // raw B prefetch (w1b row tid, 32 k)

    auto prefetch = [&](int kc) {
        const unsigned short* bsrc = w1b + (size_t)tid * 384 + kc * 32;
        rb[0] = *(const uint4*)(bsrc);
        rb[1] = *(const uint4*)(bsrc + 8);
        rb[2] = *(const uint4*)(bsrc + 16);
        rb[3] = *(const uint4*)(bsrc + 24);
        if (kc < 4) {
            const float* src = p1 + (((size_t)(row0 + r)) << 7) + kc * 32 + half * 16;
            ra[0] = *(const float4*)(src);
            ra[1] = *(const float4*)(src + 4);
            ra[2] = *(const float4*)(src + 8);
            ra[3] = *(const float4*)(src + 12);
        } else {
            const int c2 = kc * 32 - 128 + half * 16;
#pragma unroll
            for (int g = 0; g < 4; ++g) {
                ra[g]     = *(const float4*)(g0 + c2 + g * 4);
                ra[4 + g] = *(const float4*)(g1 + c2 + g * 4);
                ra[8 + g] = *(const float4*)(g2 + c2 + g * 4);
            }
        }
    };

    prefetch(0);

    for (int kc = 0; kc < 12; ++kc) {
        uint4 pa0, pa1;
        if (kc < 4) {
            pa0 = make_uint4(pk2(ra[0].x, ra[0].y), pk2(ra[0].z, ra[0].w),
                             pk2(ra[1].x, ra[1].y), pk2(ra[1].z, ra[1].w));
            pa1 = make_uint4(pk2(ra[2].x, ra[2].y), pk2(ra[2].z, ra[2].w),
                             pk2(ra[3].x, ra[3].y), pk2(ra[3].z, ra[3].w));
        } else {
            float v[16];
#pragma unroll
            for (int g = 0; g < 4; ++g) {
                v[g * 4 + 0] = fmaf(wa, ra[g].x, fmaf(wb, ra[4 + g].x, wc * ra[8 + g].x));
                v[g * 4 + 1] = fmaf(wa, ra[g].y, fmaf(wb, ra[4 + g].y, wc * ra[8 + g].y));
                v[g * 4 + 2] = fmaf(wa, ra[g].z, fmaf(wb, ra[4 + g].z, wc * ra[8 + g].z));
                v[g * 4 + 3] = fmaf(wa, ra[g].w, fmaf(wb, ra[4 + g].w, wc * ra[8 + g].w));
            }
            pa0 = make_uint4(pk2(v[0], v[1]), pk2(v[2], v[3]), pk2(v[4], v[5]), pk2(v[6], v[7]));
            pa1 = make_uint4(pk2(v[8], v[9]), pk2(v[10], v[11]), pk2(v[12], v[13]), pk2(v[14], v[15]));
        }
        const uint4 wb0 = rb[0], wb1 = rb[1], wb2 = rb[2], wb3 = rb[3];

        __syncthreads();   // WAR: prior iteration's frag reads complete
        *(uint4*)&As[r * LDB + half * 16] = pa0;
        *(uint4*)&As[r * LDB + half * 16 + 8] = pa1;
        *(uint4*)&Bs[tid * LDB + 0]  = wb0;
        *(uint4*)&Bs[tid * LDB + 8]  = wb1;
        *(uint4*)&Bs[tid * LDB + 16] = wb2;
        *(uint4*)&Bs[tid * LDB + 24] = wb3;
        __syncthreads();

        if (kc < 11) prefetch(kc + 1);   // loads in flight during frags+MFMA

        short8 af[2][2], bfv[4][2];
#pragma unroll
        for (int mt = 0; mt < 2; ++mt)
#pragma unroll
            for (int ks = 0; ks < 2; ++ks)
                af[mt][ks] = *(const short8*)&As[(wm + mt * 32 + ln) * LDB + ks * 16 + hk * 8];
#pragma unroll
        for (int nt = 0; nt < 4; ++nt)
#pragma unroll
            for (int ks = 0; ks < 2; ++ks)
                bfv[nt][ks] = *(const short8*)&Bs[(wn + nt * 32 + ln) * LDB + ks * 16 + hk * 8];
#pragma unroll
        for (int mt = 0; mt < 2; ++mt)
#pragma unroll
            for (int nt = 0; nt < 4; ++nt)
#pragma unroll
                for (int ks = 0; ks < 2; ++ks)
                    acc[mt][nt] = __builtin_amdgcn_mfma_f32_32x32x16_bf16(
                        af[mt][ks], bfv[nt][ks], acc[mt][nt], 0, 0, 0);
    }

    // ---- epilogue: bias, stats, bf16 h1 store
#pragma unroll
    for (int nt = 0; nt < 4; ++nt) {
        const int col = wn + nt * 32 + ln;
        const float bias = b1p[col];
        float ps = 0.f, pq = 0.f;
#pragma unroll
        for (int mt = 0; mt < 2; ++mt) {
#pragma unroll
            for (int e = 0; e < 16; ++e) {
                const int rl = wm + mt * 32 + (e & 3) + ((e >> 2) << 3) + (hk << 2);
                const float o = acc[mt][nt][e] + bias;
                ps += o;
                pq = fmaf(o, o, pq);
                h1b[(((size_t)(row0 + rl)) << 8) + col] = f2b(o);
            }
        }
        atomicAdd(&sSum[col], ps);
        atomicAdd(&sSq[col], pq);
    }
    __syncthreads();
    atomicAdd(&st1[tid], sSum[tid]);
    atomicAdd(&st1[256 + tid], sSq[tid]);
}

// ---------------------------------------------------------------- BN coef prep
__global__ void k_bnprep(const float* __restrict__ st, const float* __restrict__ g,
                         const float* __restrict__ be, float* __restrict__ bn,
                         int C, float invM) {
    int c = blockIdx.x * blockDim.x + threadIdx.x;
    if (c < C) {
        float mean = st[c] * invM;
        float var = st[C + c] * invM - mean * mean;
        float a = g[c] / sqrtf(var + 1e-5f);
        bn[c] = a;
        bn[C + c] = fmaf(-mean, a, be[c]);
    }
}

// ---------------------------------------------------------------- GEMM2: MFMA bf16, BN1+ReLU fused,
// register-prefetch pipeline, bf16 in/out, stats2
__global__ __launch_bounds__(256) void k_gemm2(const unsigned short* __restrict__ h1b,
                                               const unsigned short* __restrict__ w2b,
                                               const float* __restrict__ b2p,
                                               const float* __restrict__ bn1,
                                               unsigned short* __restrict__ h2b,
                                               float* __restrict__ st2) {
    __shared__ __align__(16) unsigned short As[128 * LDB];
    __shared__ __align__(16) unsigned short Bs[128 * LDB];
    __shared__ float sBNa[256], sBNb[256];
    __shared__ float sSum[128], sSq[128];

    const int tid = threadIdx.x;
    const int row0 = blockIdx.x * 128;

    sBNa[tid] = bn1[tid];
    sBNb[tid] = bn1[256 + tid];
    if (tid < 128) { sSum[tid] = 0.f; sSq[tid] = 0.f; }

    const int wave = tid >> 6, lane = tid & 63;
    const int ln = lane & 31, hk = lane >> 5;
    const int wm = (wave & 1) << 6, wn = (wave >> 1) << 6;
    const int r = tid >> 1, half = tid & 1;

    f32x16 acc[2][2];
#pragma unroll
    for (int mt = 0; mt < 2; ++mt)
#pragma unroll
        for (int nt = 0; nt < 2; ++nt)
#pragma unroll
            for (int e = 0; e < 16; ++e) acc[mt][nt][e] = 0.f;

    uint4 rA0, rA1, rB0, rB1;
    auto prefetch = [&](int kc) {
        const unsigned short* asrc = h1b + (size_t)(row0 + r) * 256 + kc * 32 + half * 16;
        rA0 = *(const uint4*)asrc;
        rA1 = *(const uint4*)(asrc + 8);
        const unsigned short* bsrc = w2b + (size_t)r * 256 + kc * 32 + half * 16;
        rB0 = *(const uint4*)bsrc;
        rB1 = *(const uint4*)(bsrc + 8);
    };

    prefetch(0);
    __syncthreads();   // sBN visible

    for (int kc = 0; kc < 8; ++kc) {
        const int k0 = kc * 32 + half * 16;
        unsigned pw[8] = {rA0.x, rA0.y, rA0.z, rA0.w, rA1.x, rA1.y, rA1.z, rA1.w};
        unsigned po[8];
#pragma unroll
        for (int gi = 0; gi < 8; ++gi) {
            float lo = b2f_lo(pw[gi]);
            float hi = b2f_hi(pw[gi]);
            lo = fmaxf(fmaf(sBNa[k0 + 2 * gi], lo, sBNb[k0 + 2 * gi]), 0.f);
            hi = fmaxf(fmaf(sBNa[k0 + 2 * gi + 1], hi, sBNb[k0 + 2 * gi + 1]), 0.f);
            po[gi] = pk2(lo, hi);
        }
        const uint4 pa0 = make_uint4(po[0], po[1], po[2], po[3]);
        const uint4 pa1 = make_uint4(po[4], po[5], po[6], po[7]);
        const uint4 qb0 = rB0, qb1 = rB1;

        __syncthreads();
        *(uint4*)&As[r * LDB + half * 16] = pa0;
        *(uint4*)&As[r * LDB + half * 16 + 8] = pa1;
        *(uint4*)&Bs[r * LDB + half * 16] = qb0;
        *(uint4*)&Bs[r * LDB + half * 16 + 8] = qb1;
        __syncthreads();

        if (kc < 7) prefetch(kc + 1);

        short8 af[2][2], bfv[2][2];
#pragma unroll
        for (int mt = 0; mt < 2; ++mt)
#pragma unroll
            for (int ks = 0; ks < 2; ++ks)
                af[mt][ks] = *(const short8*)&As[(wm + mt * 32 + ln) * LDB + ks * 16 + hk * 8];
#pragma unroll
        for (int nt = 0; nt < 2; ++nt)
#pragma unroll
            for (int ks = 0; ks < 2; ++ks)
                bfv[nt][ks] = *(const short8*)&Bs[(wn + nt * 32 + ln) * LDB + ks * 16 + hk * 8];
#pragma unroll
        for (int mt = 0; mt < 2; ++mt)
#pragma unroll
            for (int nt = 0; nt < 2; ++nt)
#pragma unroll
                for (int ks = 0; ks < 2; ++ks)
                    acc[mt][nt] = __builtin_amdgcn_mfma_f32_32x32x16_bf16(
                        af[mt][ks], bfv[nt][ks], acc[mt][nt], 0, 0, 0);
    }

#pragma unroll
    for (int nt = 0; nt < 2; ++nt) {
        const int col = wn + nt * 32 + ln;
        const float bias = b2p[col];
        float ps = 0.f, pq = 0.f;
#pragma unroll
        for (int mt = 0; mt < 2; ++mt) {
#pragma unroll
            for (int e = 0; e < 16; ++e) {
                const int rl = wm + mt * 32 + (e & 3) + ((e >> 2) << 3) + (hk << 2);
                const float o = acc[mt][nt][e] + bias;
                ps += o;
                pq = fmaf(o, o, pq);
                h2b[(((size_t)(row0 + rl)) << 7) + col] = f2b(o);
            }
        }
        atomicAdd(&sSum[col], ps);
        atomicAdd(&sSq[col], pq);
    }
    __syncthreads();
    if (tid < 128) {
        atomicAdd(&st2[tid], sSum[tid]);
        atomicAdd(&st2[128 + tid], sSq[tid]);
    }
}

// ---------------------------------------------------------------- pool pass (bf16 h2)
__global__ __launch_bounds__(256) void k_pool(const unsigned short* __restrict__ h2b,
                                              const float* __restrict__ bn2,
                                              float* __restrict__ psum,
                                              int* __restrict__ pmax) {
    const int b = blockIdx.y;
    const int n0 = blockIdx.x * 256;
    const int tid = threadIdx.x;
    const int c = tid & 127, rh = tid >> 7;
    const float a = bn2[c], bc = bn2[128 + c];
    const unsigned short* base = h2b + (((size_t)b * NN + n0 + rh) << 7) + c;
    float s = 0.f, m = 0.f;
    for (int i = 0; i < 128; ++i) {
        float v = __uint_as_float((unsigned)base[(size_t)i * 256] << 16);
        float x = fmaxf(fmaf(a, v, bc), 0.f);
        s += x;
        m = fmaxf(m, x);
    }
    __shared__ float rs[256];
    __shared__ float rm[256];
    rs[tid] = s; rm[tid] = m;
    __syncthreads();
    if (tid < 128) {
        float ts = rs[tid] + rs[tid + 128];
        float tm = fmaxf(rm[tid], rm[tid + 128]);
        atomicAdd(&psum[b * 128 + c], ts);
        atomicMax(&pmax[b * 128 + c], __float_as_int(tm));
    }
}

// ---------------------------------------------------------------- SE attention
__global__ __launch_bounds__(1024) void k_attn(const float* __restrict__ psum,
                                               const int* __restrict__ pmax,
                                               const float* __restrict__ fa1,
                                               const float* __restrict__ fa2,
                                               const float* __restrict__ bn2,
                                               float* __restrict__ sa,
                                               float* __restrict__ sb) {
    __shared__ float tS[128];
    const int tid = threadIdx.x;
    if (tid < 128) {
        const int b = tid >> 4, j = tid & 15;
        float da = 0.f, dm = 0.f;
        for (int cc = 0; cc < 128; ++cc) {
            float f = fa1[j * 128 + cc];
            da = fmaf(psum[b * 128 + cc] * (1.0f / 16384.0f), f, da);
            dm = fmaf(__int_as_float(pmax[b * 128 + cc]), f, dm);
        }
        tS[tid] = fmaxf(da, 0.f) + fmaxf(dm, 0.f);
    }
    __syncthreads();
    const int b = tid >> 7, c = tid & 127;
    float s = 0.f;
#pragma unroll
    for (int j = 0; j < 16; ++j) s = fmaf(tS[b * 16 + j], fa2[c * 16 + j], s);
    const float sc = 1.f / (1.f + expf(-s));
    sa[b * 128 + c] = bn2[c] * sc;
    sb[b * 128 + c] = bn2[128 + c] * sc;
}

// ---------------------------------------------------------------- final (bf16 h2 -> fp32 out)
__global__ void k_final(const unsigned short* __restrict__ h2b, const float* __restrict__ sa,
                        const float* __restrict__ sb, float* __restrict__ out) {
    const size_t i = (size_t)blockIdx.x * blockDim.x + threadIdx.x;  // 8-elem group
    const int cg = (int)(i & 15) * 8;
    const size_t row = i >> 4;
    const int b = (int)(row >> 14);
    const uint4 h = *(const uint4*)(h2b + (row << 7) + cg);
    const float4 A0 = *(const float4*)&sa[b * 128 + cg];
    const float4 A1 = *(const float4*)&sa[b * 128 + cg + 4];
    const float4 B0 = *(const float4*)&sb[b * 128 + cg];
    const float4 B1 = *(const float4*)&sb[b * 128 + cg + 4];
    float4 o0, o1;
    o0.x = fmaxf(fmaf(A0.x, b2f_lo(h.x), B0.x), 0.f);
    o0.y = fmaxf(fmaf(A0.y, b2f_hi(h.x), B0.y), 0.f);
    o0.z = fmaxf(fmaf(A0.z, b2f_lo(h.y), B0.z), 0.f);
    o0.w = fmaxf(fmaf(A0.w, b2f_hi(h.y), B0.w), 0.f);
    o1.x = fmaxf(fmaf(A1.x, b2f_lo(h.z), B1.x), 0.f);
    o1.y = fmaxf(fmaf(A1.y, b2f_hi(h.z), B1.y), 0.f);
    o1.z = fmaxf(fmaf(A1.z, b2f_lo(h.w), B1.z), 0.f);
    o1.w = fmaxf(fmaf(A1.w, b2f_hi(h.w), B1.w), 0.f);
    *(float4*)(out + (row << 7) + cg) = o0;
    *(float4*)(out + (row << 7) + cg + 4) = o1;
}

// ---------------------------------------------------------------- launch
extern "C" void kernel_launch(void* const* d_in, const int* in_sizes, int n_in,
                              void* d_out, int out_size, void* d_ws, size_t ws_size,
                              hipStream_t stream) {
    const float* xyz1 = (const float*)d_in[0];
    const float* xyz2 = (const float*)d_in[1];
    const float* p1   = (const float*)d_in[2];
    const float* p2   = (const float*)d_in[3];
    const float* w1   = (const float*)d_in[4];
    const float* b1   = (const float*)d_in[5];
    const float* g1   = (const float*)d_in[6];
    const float* be1  = (const float*)d_in[7];
    const float* w2   = (const float*)d_in[8];
    const float* b2   = (const float*)d_in[9];
    const float* g2   = (const float*)d_in[10];
    const float* be2  = (const float*)d_in[11];
    const float* fa1  = (const float*)d_in[12];
    const float* fa2  = (const float*)d_in[13];
    float* out = (float*)d_out;

    char* ws = (char*)d_ws;
    int*   idx  = (int*)ws;                                   // 1.57 MB
    float* wgt  = (float*)(ws + 1572864);                     // 1.57 MB
    unsigned short* h1b = (unsigned short*)(ws + 3145728);    // 67 MB bf16   [ends 70254592]
    unsigned short* h2b = (unsigned short*)(ws + 70254592);   // 33.5 MB bf16 [ends 103809024]
    float* st1  = (float*)(ws + 103809024);                   // 512 f
    float* bn1  = st1 + 512;                                  // 512 f
    float* st2  = bn1 + 512;                                  // 256 f
    float* bn2  = st2 + 256;                                  // 256 f
    float* psum = bn2 + 256;                                  // 1024 f
    int*   pmax = (int*)(psum + 1024);                        // 1024 i
    float* sa   = (float*)(pmax + 1024);                      // 1024 f
    float* sb   = sa + 1024;                                  // 1024 f
    unsigned short* w1b = (unsigned short*)(sb + 1024);       // 98304 bf16  [ends 104028160]
    unsigned short* w2b = w1b + 98304;                        // 32768 bf16  [ends 104093696]
    float4* xyz2p = (float4*)(ws + 104857600);                // 256 KB @ 100 MiB — PAST w2b end (prev round overlapped!)

    k_init<<<1, 1024, 0, stream>>>(st1, st2, psum, pmax);
    k_wprep<<<(H1 * 384 + 255) / 256, 256, 0, stream>>>(w1, w2, w1b, w2b);
    k_xyzprep<<<(BB * SS + 255) / 256, 256, 0, stream>>>(xyz2, xyz2p);
    k_knn<<<dim3(NN / 64, BB), 256, 0, stream>>>(xyz1, xyz2p, idx, wgt);
    k_gemm1<<<MM / 128, 256, 0, stream>>>(p1, p2, idx, wgt, w1b, b1, h1b, st1);
    k_bnprep<<<1, 256, 0, stream>>>(st1, g1, be1, bn1, 256, 1.0f / (float)MM);
    k_gemm2<<<MM / 128, 256, 0, stream>>>(h1b, w2b, b2, bn1, h2b, st2);
    k_bnprep<<<1, 128, 0, stream>>>(st2, g2, be2, bn2, 128, 1.0f / (float)MM);
    k_pool<<<dim3(NN / 256, BB), 256, 0, stream>>>(h2b, bn2, psum, pmax);
    k_attn<<<1, 1024, 0, stream>>>(psum, pmax, fa1, fa2, bn2, sa, sb);
    k_final<<<(MM * H2 / 8) / 256, 256, 0, stream>>>(h2b, sa, sb, out);
}